// Round 3
// baseline (3525.398 us; speedup 1.0000x reference)
//
#include <hip/hip_runtime.h>
#include <math.h>

#define TT 16
#define BB 32
#define NN 256
#define DD 128
#define HH 16
#define NSTEPS 5
#define SKIPF 0.3f
#define EPSF 1e-8f

typedef __attribute__((ext_vector_type(8))) short bf16x8;
typedef __attribute__((ext_vector_type(4))) float f32x4;

__device__ __forceinline__ unsigned short f2bf(float f) {
    union { float f; unsigned u; } v; v.f = f;
    unsigned r = (v.u + 0x7FFF + ((v.u >> 16) & 1)) >> 16;
    return (unsigned short)r;
}
__device__ __forceinline__ unsigned pack2(unsigned short a, unsigned short b) {
    return (unsigned)a | ((unsigned)b << 16);
}
__device__ __forceinline__ float sigmoidf_(float x) {
    return 1.0f / (1.0f + __expf(-x));
}
__device__ __forceinline__ float tanhf_(float x) {
    // tanh(x) = 1 - 2/(e^{2x}+1); saturates correctly for |x| large
    return 1.0f - 2.0f / (__expf(2.0f * x) + 1.0f);
}

// ---------------------------------------------------------------------------
// buildV: V[b,n,h*128+d] = bf16( x[b,n,d]*Wgl[h,d] / (||x*w_h|| + eps) )
// grid = B*N (8192) blocks x 128 threads
// ---------------------------------------------------------------------------
__global__ __launch_bounds__(128) void k_buildV(const float* __restrict__ x,
                                                const float* __restrict__ Wgl,
                                                unsigned short* __restrict__ V) {
    int bid = blockIdx.x;
    int b = bid >> 8, n = bid & 255;
    int d = threadIdx.x;
    __shared__ float part[16][2];
    float xv = x[(((b << 8) + n) << 7) + d];
    float vv[16];
    int wave = d >> 6, lane = d & 63;
    #pragma unroll
    for (int h = 0; h < 16; ++h) {
        float v = xv * Wgl[(h << 7) + d];
        vv[h] = v;
        float s = v * v;
        #pragma unroll
        for (int off = 32; off; off >>= 1) s += __shfl_down(s, off, 64);
        if (lane == 0) part[h][wave] = s;
    }
    __syncthreads();
    unsigned short* Vr = V + ((size_t)((b << 8) + n) << 11);
    #pragma unroll
    for (int h = 0; h < 16; ++h) {
        float inv = 1.0f / (sqrtf(part[h][0] + part[h][1]) + EPSF);
        Vr[(h << 7) + d] = f2bf(vv[h] * inv);
    }
}

// ---------------------------------------------------------------------------
// xT: xT[b][d][n] = bf16(x[b][n][d]);  grid = 32*32 blocks x 256 thr
// ---------------------------------------------------------------------------
__global__ __launch_bounds__(256) void k_xT(const float* __restrict__ x,
                                            unsigned short* __restrict__ xT) {
    int bid = blockIdx.x;
    int b = bid >> 5; int r = bid & 31; int d0 = (r >> 3) << 5; int n0 = (r & 7) << 5;
    __shared__ float t[32][33];
    int tid = threadIdx.x;
    int i = tid >> 5, j = tid & 31;
    #pragma unroll
    for (int s = 0; s < 4; ++s) {
        int nl = (s << 3) + i;
        t[nl][j] = x[(((b << 8) + n0 + nl) << 7) + d0 + j];
    }
    __syncthreads();
    #pragma unroll
    for (int s = 0; s < 4; ++s) {
        int dd = (s << 3) + i;
        xT[(((b << 7) + d0 + dd) << 8) + n0 + j] = f2bf(t[j][dd]);
    }
}

// ---------------------------------------------------------------------------
// wprep: bf16-transposed weights WT[dout][k]
// ---------------------------------------------------------------------------
__global__ __launch_bounds__(256) void k_wprep(const float* __restrict__ Wa,
                                               const float* __restrict__ Wr,
                                               const float* __restrict__ Wz,
                                               const float* __restrict__ Wh,
                                               unsigned short* __restrict__ WaT,
                                               unsigned short* __restrict__ WrT,
                                               unsigned short* __restrict__ WzT,
                                               unsigned short* __restrict__ WhT) {
    int idx = blockIdx.x * 256 + threadIdx.x;     // 0..32767
    if (idx < 16384) {
        int dout = idx >> 7, din = idx & 127;
        WaT[idx] = f2bf(Wa[(din << 7) + dout]);
    }
    {
        int dout = idx >> 8, dk = idx & 255;
        WrT[idx] = f2bf(Wr[(dk << 7) + dout]);
        WzT[idx] = f2bf(Wz[(dk << 7) + dout]);
        WhT[idx] = f2bf(Wh[(dk << 7) + dout]);
    }
}

// ---------------------------------------------------------------------------
// gram (stage A): partial V V^T over a K-slice.
// grid = 256*KS blocks (tileid = bid&255 -> b,rg ; kci = bid>>8), 256 threads.
// Each block: 32 rows x 256 cols x K=klen, f32 partial -> Sp.
// 4 blocks/CU (LDS 37KB) x 4 waves = 16 waves/CU.
// ---------------------------------------------------------------------------
__global__ __launch_bounds__(256) void k_gram(const unsigned short* __restrict__ V,
                                              float* __restrict__ Sp, int klen) {
    int bid = blockIdx.x;
    int tileid = bid & 255;
    int b = tileid & 31, rg = tileid >> 5;
    int kci = bid >> 8;
    int n0 = rg << 5;
    int tid = threadIdx.x;
    int wave = tid >> 6, lane = tid & 63;
    int m16 = lane & 15, quad = lane >> 4;

    __shared__ unsigned short Vs[256 * 72];   // 36.9KB

    f32x4 acc[2][4];
    #pragma unroll
    for (int rb = 0; rb < 2; ++rb)
        #pragma unroll
        for (int cb = 0; cb < 4; ++cb) acc[rb][cb] = (f32x4){0.f, 0.f, 0.f, 0.f};

    const unsigned short* Vb = V + ((size_t)b << 19);  // b*256*2048
    int k0 = kci * klen;

    for (int kc = k0; kc < k0 + klen; kc += 64) {
        __syncthreads();
        {
            const unsigned short* src = Vb + ((size_t)tid << 11) + kc;
            unsigned short* dst = Vs + tid * 72;
            #pragma unroll
            for (int i = 0; i < 8; ++i)
                *(int4*)(dst + (i << 3)) = *(const int4*)(src + (i << 3));
        }
        __syncthreads();
        #pragma unroll
        for (int ks = 0; ks < 2; ++ks) {
            bf16x8 afr[2], bfr[4];
            #pragma unroll
            for (int rb = 0; rb < 2; ++rb)
                afr[rb] = *(const bf16x8*)(Vs + (n0 + (rb << 4) + m16) * 72 + (ks << 5) + (quad << 3));
            #pragma unroll
            for (int cb = 0; cb < 4; ++cb)
                bfr[cb] = *(const bf16x8*)(Vs + ((wave << 6) + (cb << 4) + m16) * 72 + (ks << 5) + (quad << 3));
            #pragma unroll
            for (int rb = 0; rb < 2; ++rb)
                #pragma unroll
                for (int cb = 0; cb < 4; ++cb)
                    acc[rb][cb] = __builtin_amdgcn_mfma_f32_16x16x32_bf16(afr[rb], bfr[cb], acc[rb][cb], 0, 0, 0);
        }
    }

    float* out = Sp + ((size_t)((kci << 8) + tileid) << 13);   // tile of 32*256 f32
    #pragma unroll
    for (int rb = 0; rb < 2; ++rb)
        #pragma unroll
        for (int r = 0; r < 4; ++r) {
            int row = (rb << 4) + (quad << 2) + r;
            #pragma unroll
            for (int cb = 0; cb < 4; ++cb) {
                int col = (wave << 6) + (cb << 4) + m16;
                out[(row << 8) + col] = acc[rb][cb][r];
            }
        }
}

// ---------------------------------------------------------------------------
// attfin (stage B): S = sum_kci Sp ; relu ; rowsum ; A = 0.3A + 0.7 S/rowsum
// grid = 512 blocks (b = bid&31, rg16 = bid>>5 -> 16 rows), 256 threads (=col)
// ---------------------------------------------------------------------------
__global__ __launch_bounds__(256) void k_attfin(const float* __restrict__ Sp, int KS,
                                                float* __restrict__ A,
                                                unsigned short* __restrict__ Abf) {
    int bid = blockIdx.x;
    int b = bid & 31;
    int rg16 = bid >> 5;       // 0..15
    int col = threadIdx.x;
    int wave = col >> 6, lane = col & 63;
    __shared__ float rsW[4][16];
    float vals[16];

    #pragma unroll
    for (int i = 0; i < 16; ++i) {
        int R = (rg16 << 4) + i;
        int tileid = (((R >> 5) << 5) | b);
        size_t base = ((size_t)tileid << 13) + ((size_t)(R & 31) << 8) + col;
        float v = 0.f;
        for (int kci = 0; kci < KS; ++kci)
            v += Sp[base + ((size_t)kci << 21)];
        v = fmaxf(v, 0.f);
        vals[i] = v;
        float s = v;
        #pragma unroll
        for (int off = 32; off; off >>= 1) s += __shfl_down(s, off, 64);
        if (lane == 0) rsW[wave][i] = s;
    }
    __syncthreads();
    #pragma unroll
    for (int i = 0; i < 16; ++i) {
        int R = (rg16 << 4) + i;
        float tot = rsW[0][i] + rsW[1][i] + rsW[2][i] + rsW[3][i];
        float inv = (1.0f - SKIPF) / (tot + 16.0f * EPSF);
        size_t idx = (((size_t)(b << 8) + R) << 8) + col;
        float an = SKIPF * A[idx] + vals[i] * inv;
        A[idx] = an;
        Abf[idx] = f2bf(an);
    }
}

// ---------------------------------------------------------------------------
// step: fused GGNN/GRU step for 16 rows. grid = 512 blocks x 256 threads.
// 2 blocks/CU x 4 waves = 8 waves/CU.
// ---------------------------------------------------------------------------
__global__ __launch_bounds__(256) void k_step(
    const unsigned short* __restrict__ Abf,
    const unsigned short* __restrict__ hT,
    const float* __restrict__ hf,
    const unsigned short* __restrict__ WaT, const float* __restrict__ ba,
    const unsigned short* __restrict__ WrT, const float* __restrict__ br,
    const unsigned short* __restrict__ WzT, const float* __restrict__ bz,
    const unsigned short* __restrict__ WhT, const float* __restrict__ bh,
    float* __restrict__ hf_o, unsigned short* __restrict__ hT_o) {

    int bid = blockIdx.x;
    int b = bid & 31, rg = bid >> 5;     // rg 0..15
    int n0 = rg << 4;
    int tid = threadIdx.x;
    int wave = tid >> 6, lane = tid & 63;
    int m16 = lane & 15, quad = lane >> 4;
    int wcol = wave << 5;

    __shared__ unsigned short msgS[16 * 136];   // 4.3KB
    __shared__ unsigned short ahS[16 * 264];    // 8.4KB; k 0..127 = a, 128..255 = h (later r*h)

    // stage h-half of ahS (f32 -> bf16): 16 rows x 128 = 2048 elems, 8/thread
    {
        int row = tid >> 4, ch = (tid & 15) << 3;
        const float* src = hf + (((size_t)((b << 8) + n0 + row)) << 7) + ch;
        unsigned short t0[8];
        #pragma unroll
        for (int i = 0; i < 8; ++i) t0[i] = f2bf(src[i]);
        uint4 o;
        o.x = pack2(t0[0], t0[1]); o.y = pack2(t0[2], t0[3]);
        o.z = pack2(t0[4], t0[5]); o.w = pack2(t0[6], t0[7]);
        *(uint4*)(ahS + row * 264 + 128 + ch) = o;
    }

    // ---- bmm: msg = A_tile @ h  (K=256) ----
    f32x4 acc[2];
    #pragma unroll
    for (int cb = 0; cb < 2; ++cb) acc[cb] = (f32x4){0.f, 0.f, 0.f, 0.f};

    const unsigned short* Ab = Abf + ((size_t)b << 16) + ((size_t)n0 << 8);
    const unsigned short* hTb = hT + ((size_t)b << 15);
    #pragma unroll
    for (int ks = 0; ks < 8; ++ks) {
        bf16x8 af = *(const bf16x8*)(Ab + (m16 << 8) + (ks << 5) + (quad << 3));
        #pragma unroll
        for (int cb = 0; cb < 2; ++cb) {
            bf16x8 bf = *(const bf16x8*)(hTb + ((wcol + (cb << 4) + m16) << 8) + (ks << 5) + (quad << 3));
            acc[cb] = __builtin_amdgcn_mfma_f32_16x16x32_bf16(af, bf, acc[cb], 0, 0, 0);
        }
    }
    #pragma unroll
    for (int cb = 0; cb < 2; ++cb)
        #pragma unroll
        for (int r = 0; r < 4; ++r)
            msgS[((quad << 2) + r) * 136 + wcol + (cb << 4) + m16] = f2bf(acc[cb][r]);
    __syncthreads();   // also covers h-half staging

    // ---- a = msg @ Wa + ba  (K=128) ----
    #pragma unroll
    for (int cb = 0; cb < 2; ++cb) acc[cb] = (f32x4){0.f, 0.f, 0.f, 0.f};
    #pragma unroll
    for (int ks = 0; ks < 4; ++ks) {
        bf16x8 af = *(const bf16x8*)(msgS + m16 * 136 + (ks << 5) + (quad << 3));
        #pragma unroll
        for (int cb = 0; cb < 2; ++cb) {
            bf16x8 bf = *(const bf16x8*)(WaT + ((wcol + (cb << 4) + m16) << 7) + (ks << 5) + (quad << 3));
            acc[cb] = __builtin_amdgcn_mfma_f32_16x16x32_bf16(af, bf, acc[cb], 0, 0, 0);
        }
    }
    {
        #pragma unroll
        for (int cb = 0; cb < 2; ++cb) {
            float bav = ba[wcol + (cb << 4) + m16];
            #pragma unroll
            for (int r = 0; r < 4; ++r)
                ahS[((quad << 2) + r) * 264 + wcol + (cb << 4) + m16] = f2bf(acc[cb][r] + bav);
        }
    }
    __syncthreads();

    // h_old f32 (for r*h and final update)
    float hv[2][4];
    #pragma unroll
    for (int cb = 0; cb < 2; ++cb)
        #pragma unroll
        for (int r = 0; r < 4; ++r)
            hv[cb][r] = hf[(((size_t)((b << 8) + n0 + (quad << 2) + r)) << 7) + wcol + (cb << 4) + m16];

    // ---- r and z (K=256 over [a|h]) ----
    f32x4 racc[2], zacc[2];
    #pragma unroll
    for (int cb = 0; cb < 2; ++cb) {
        racc[cb] = (f32x4){0.f, 0.f, 0.f, 0.f};
        zacc[cb] = (f32x4){0.f, 0.f, 0.f, 0.f};
    }
    #pragma unroll
    for (int ks = 0; ks < 8; ++ks) {
        bf16x8 af = *(const bf16x8*)(ahS + m16 * 264 + (ks << 5) + (quad << 3));
        #pragma unroll
        for (int cb = 0; cb < 2; ++cb) {
            int dout = wcol + (cb << 4) + m16;
            bf16x8 bfr = *(const bf16x8*)(WrT + (dout << 8) + (ks << 5) + (quad << 3));
            bf16x8 bfz = *(const bf16x8*)(WzT + (dout << 8) + (ks << 5) + (quad << 3));
            racc[cb] = __builtin_amdgcn_mfma_f32_16x16x32_bf16(af, bfr, racc[cb], 0, 0, 0);
            zacc[cb] = __builtin_amdgcn_mfma_f32_16x16x32_bf16(af, bfz, zacc[cb], 0, 0, 0);
        }
    }
    float zv[2][4];
    #pragma unroll
    for (int cb = 0; cb < 2; ++cb) {
        float brv = br[wcol + (cb << 4) + m16];
        float bzv = bz[wcol + (cb << 4) + m16];
        #pragma unroll
        for (int r = 0; r < 4; ++r) {
            racc[cb][r] = sigmoidf_(racc[cb][r] + brv);
            zv[cb][r]   = sigmoidf_(zacc[cb][r] + bzv);
        }
    }
    __syncthreads();   // all ahS h-half reads done -> safe to overwrite

    #pragma unroll
    for (int cb = 0; cb < 2; ++cb)
        #pragma unroll
        for (int r = 0; r < 4; ++r)
            ahS[((quad << 2) + r) * 264 + 128 + wcol + (cb << 4) + m16] = f2bf(racc[cb][r] * hv[cb][r]);
    __syncthreads();

    // ---- h_tilde (K=256 over [a|r*h]) ----
    #pragma unroll
    for (int cb = 0; cb < 2; ++cb) acc[cb] = (f32x4){0.f, 0.f, 0.f, 0.f};
    #pragma unroll
    for (int ks = 0; ks < 8; ++ks) {
        bf16x8 af = *(const bf16x8*)(ahS + m16 * 264 + (ks << 5) + (quad << 3));
        #pragma unroll
        for (int cb = 0; cb < 2; ++cb) {
            bf16x8 bf = *(const bf16x8*)(WhT + ((wcol + (cb << 4) + m16) << 8) + (ks << 5) + (quad << 3));
            acc[cb] = __builtin_amdgcn_mfma_f32_16x16x32_bf16(af, bf, acc[cb], 0, 0, 0);
        }
    }

    // ---- update + writes ----
    #pragma unroll
    for (int cb = 0; cb < 2; ++cb) {
        float bhv = bh[wcol + (cb << 4) + m16];
        int col = wcol + (cb << 4) + m16;
        unsigned short pk[4];
        #pragma unroll
        for (int r = 0; r < 4; ++r) {
            float ht = tanhf_(acc[cb][r] + bhv);
            float hn = hv[cb][r] + zv[cb][r] * (ht - hv[cb][r]);
            int row = n0 + (quad << 2) + r;
            hf_o[(((size_t)((b << 8) + row)) << 7) + col] = hn;
            pk[r] = f2bf(hn);
        }
        uint2 p;
        p.x = pack2(pk[0], pk[1]); p.y = pack2(pk[2], pk[3]);
        *(uint2*)(hT_o + (((size_t)((b << 7) + col)) << 8) + n0 + (quad << 2)) = p;
    }
}

// ---------------------------------------------------------------------------
__global__ __launch_bounds__(256) void k_fc(const float* __restrict__ h,
                                            const float* __restrict__ Wfc,
                                            const float* __restrict__ bfc,
                                            float* __restrict__ out) {
    int b = blockIdx.x;
    int tid = threadIdx.x;
    float a0 = 0.0f, a1 = 0.0f;
    const float* hb = &h[b * 32768];
    for (int i = tid; i < 32768; i += 256) {
        float v = hb[i];
        const float2 w = *(const float2*)&Wfc[i * 2];
        a0 = fmaf(v, w.x, a0);
        a1 = fmaf(v, w.y, a1);
    }
    int wave = tid >> 6, lane = tid & 63;
    #pragma unroll
    for (int off = 32; off; off >>= 1) {
        a0 += __shfl_down(a0, off, 64);
        a1 += __shfl_down(a1, off, 64);
    }
    __shared__ float r0[4], r1[4];
    if (lane == 0) { r0[wave] = a0; r1[wave] = a1; }
    __syncthreads();
    if (tid == 0) {
        out[b * 2 + 0] = r0[0] + r0[1] + r0[2] + r0[3] + bfc[0];
        out[b * 2 + 1] = r1[0] + r1[1] + r1[2] + r1[3] + bfc[1];
    }
}

// ---------------------------------------------------------------------------
extern "C" void kernel_launch(void* const* d_in, const int* in_sizes, int n_in,
                              void* d_out, int out_size, void* d_ws, size_t ws_size,
                              hipStream_t stream) {
    const float* x_all    = (const float*)d_in[0];
    const float* supports = (const float*)d_in[1];
    const float* Wgl = (const float*)d_in[2];
    const float* Wa  = (const float*)d_in[3];
    const float* ba  = (const float*)d_in[4];
    const float* Wr  = (const float*)d_in[5];
    const float* br  = (const float*)d_in[6];
    const float* Wz  = (const float*)d_in[7];
    const float* bz  = (const float*)d_in[8];
    const float* Wh  = (const float*)d_in[9];
    const float* bh  = (const float*)d_in[10];
    const float* Wfc = (const float*)d_in[11];
    const float* bfc = (const float*)d_in[12];
    float* out = (float*)d_out;

    char* p = (char*)d_ws;
    auto alloc = [&](size_t bytes) { char* r = p; p += (bytes + 255) & ~(size_t)255; return r; };

    float* A            = (float*)alloc((size_t)BB * NN * NN * 4);            // 8 MB
    unsigned short* V   = (unsigned short*)alloc((size_t)BB * NN * 2048 * 2); // 32 MB
    unsigned short* Abf = (unsigned short*)alloc((size_t)BB * NN * NN * 2);   // 4 MB
    unsigned short* xT  = (unsigned short*)alloc((size_t)BB * DD * NN * 2);   // 2 MB
    float* hf0          = (float*)alloc((size_t)BB * NN * DD * 4);            // 4 MB
    float* hf1          = (float*)alloc((size_t)BB * NN * DD * 4);
    unsigned short* hT0 = (unsigned short*)alloc((size_t)BB * DD * NN * 2);
    unsigned short* hT1 = (unsigned short*)alloc((size_t)BB * DD * NN * 2);
    unsigned short* WaT = (unsigned short*)alloc(128 * 128 * 2);
    unsigned short* WrT = (unsigned short*)alloc(256 * 128 * 2);
    unsigned short* WzT = (unsigned short*)alloc(256 * 128 * 2);
    unsigned short* WhT = (unsigned short*)alloc(256 * 128 * 2);

    // K-split factor for gram partials, limited by remaining workspace
    size_t used = (size_t)(p - (char*)d_ws);
    size_t avail = (ws_size > used) ? ws_size - used : 0;
    size_t tileBytes = (size_t)256 * 32 * 256 * 4;            // 8 MB per K-slice
    int KS = 1;
    if (avail >= 4 * tileBytes + 1024) KS = 4;
    else if (avail >= 2 * tileBytes + 1024) KS = 2;
    float* Sp = (float*)alloc((size_t)KS * tileBytes);
    int klen = 2048 / KS;

    hipMemcpyAsync(A, supports, (size_t)BB * NN * NN * sizeof(float),
                   hipMemcpyDeviceToDevice, stream);
    k_wprep<<<128, 256, 0, stream>>>(Wa, Wr, Wz, Wh, WaT, WrT, WzT, WhT);

    for (int t = 0; t < TT; ++t) {
        const float* xt = x_all + (size_t)t * BB * NN * DD;
        k_buildV<<<BB * NN, 128, 0, stream>>>(xt, Wgl, V);
        k_xT<<<BB * 32, 256, 0, stream>>>(xt, xT);
        k_gram<<<256 * KS, 256, 0, stream>>>(V, Sp, klen);
        k_attfin<<<512, 256, 0, stream>>>(Sp, KS, A, Abf);

        const unsigned short* hT_in = xT;
        const float* hf_in = xt;
        for (int s = 0; s < NSTEPS; ++s) {
            float* hf_out = (s & 1) ? hf1 : hf0;
            unsigned short* hT_out = (s & 1) ? hT1 : hT0;
            k_step<<<512, 256, 0, stream>>>(Abf, hT_in, hf_in,
                                            WaT, ba, WrT, br, WzT, bz, WhT, bh,
                                            hf_out, hT_out);
            hf_in = hf_out;
            hT_in = hT_out;
        }
    }
    k_fc<<<BB, 256, 0, stream>>>(hf0, Wfc, bfc, out);
}

// Round 5
// 1985.568 us; speedup vs baseline: 1.7755x; 1.7755x over previous
//
#include <hip/hip_runtime.h>
#include <math.h>

#define TT 16
#define BB 32
#define NN 256
#define DD 128
#define NSTEPS 5
#define SKIPF 0.3f
#define EPSF 1e-8f
#define GT 2            // t-group size for V materialization (V aliases hT0+hT1)

// Workspace budget note: round 4 failed post-timing with ~192.43 MB allocated
// (ws_size is almost certainly 192 MB; the ~225 KB overflow corrupted the
// harness's pristine input copies -> replays diverged). This version uses
// 64 (AttA) + 32 (hT0) + 32 (hT1) + ~0.22 MB = ~128.2 MB. V (64 MB, GT=2)
// aliases hT0+hT1, which are written only after all gram work completes.

typedef __attribute__((ext_vector_type(8))) short bf16x8;
typedef __attribute__((ext_vector_type(4))) float f32x4;

__device__ __forceinline__ unsigned short f2bf(float f) {
    union { float f; unsigned u; } v; v.f = f;
    unsigned r = (v.u + 0x7FFF + ((v.u >> 16) & 1)) >> 16;
    return (unsigned short)r;
}
__device__ __forceinline__ float bf2f(unsigned short u) {
    union { unsigned u; float f; } v; v.u = ((unsigned)u) << 16; return v.f;
}
__device__ __forceinline__ unsigned pack2(unsigned short a, unsigned short b) {
    return (unsigned)a | ((unsigned)b << 16);
}
__device__ __forceinline__ float sigmoidf_(float x) {
    return 1.0f / (1.0f + __expf(-x));
}
__device__ __forceinline__ float tanhf_(float x) {
    return 1.0f - 2.0f / (__expf(2.0f * x) + 1.0f);
}

// ---------------------------------------------------------------------------
// buildV (per t-group): V[tbl,n,h*128+d] = bf16( x*Wgl[h]/(||x*w_h||+eps) )
// grid = GT*32*256 blocks x 128 threads; x pre-offset to group start
// ---------------------------------------------------------------------------
__global__ __launch_bounds__(128) void k_buildV(const float* __restrict__ x,
                                                const float* __restrict__ Wgl,
                                                unsigned short* __restrict__ V) {
    int bid = blockIdx.x;
    int tbl = bid >> 8, n = bid & 255;
    int d = threadIdx.x;
    __shared__ float part[16][2];
    float xv = x[((size_t)(tbl * 256 + n) << 7) + d];
    float vv[16];
    int wave = d >> 6, lane = d & 63;
    #pragma unroll
    for (int h = 0; h < 16; ++h) {
        float v = xv * Wgl[(h << 7) + d];
        vv[h] = v;
        float s = v * v;
        #pragma unroll
        for (int off = 32; off; off >>= 1) s += __shfl_down(s, off, 64);
        if (lane == 0) part[h][wave] = s;
    }
    __syncthreads();
    unsigned short* Vr = V + ((size_t)(tbl * 256 + n) << 11);
    #pragma unroll
    for (int h = 0; h < 16; ++h) {
        float inv = 1.0f / (sqrtf(part[h][0] + part[h][1]) + EPSF);
        Vr[(h << 7) + d] = f2bf(vv[h] * inv);
    }
}

// ---------------------------------------------------------------------------
// gram (per t-group): attn = 0.7 * rownorm(relu(V V^T))  -> bf16
// grid = 8 rg x (GT*32) tbl, 256 threads.
// ---------------------------------------------------------------------------
__global__ __launch_bounds__(256) void k_gram(const unsigned short* __restrict__ V,
                                              unsigned short* __restrict__ attn) {
    int bid = blockIdx.x;
    int tbl = bid & (GT * 32 - 1);
    int rg  = bid / (GT * 32);          // 0..7
    int n0 = rg << 5;
    int tid = threadIdx.x;
    int wave = tid >> 6, lane = tid & 63;
    int m16 = lane & 15, quad = lane >> 4;

    __shared__ unsigned short Vs[256 * 72];   // 36.9KB
    __shared__ float rsum[4][32];

    f32x4 acc[2][4];
    #pragma unroll
    for (int rb = 0; rb < 2; ++rb)
        #pragma unroll
        for (int cb = 0; cb < 4; ++cb) acc[rb][cb] = (f32x4){0.f, 0.f, 0.f, 0.f};

    const unsigned short* Vb = V + ((size_t)tbl << 19);   // tbl*256*2048

    for (int kc = 0; kc < 2048; kc += 64) {
        __syncthreads();
        {
            const unsigned short* src = Vb + ((size_t)tid << 11) + kc;
            unsigned short* dst = Vs + tid * 72;
            #pragma unroll
            for (int i = 0; i < 8; ++i)
                *(int4*)(dst + (i << 3)) = *(const int4*)(src + (i << 3));
        }
        __syncthreads();
        #pragma unroll
        for (int ks = 0; ks < 2; ++ks) {
            bf16x8 afr[2], bfr[4];
            #pragma unroll
            for (int rb = 0; rb < 2; ++rb)
                afr[rb] = *(const bf16x8*)(Vs + (n0 + (rb << 4) + m16) * 72 + (ks << 5) + (quad << 3));
            #pragma unroll
            for (int cb = 0; cb < 4; ++cb)
                bfr[cb] = *(const bf16x8*)(Vs + ((wave << 6) + (cb << 4) + m16) * 72 + (ks << 5) + (quad << 3));
            #pragma unroll
            for (int rb = 0; rb < 2; ++rb)
                #pragma unroll
                for (int cb = 0; cb < 4; ++cb)
                    acc[rb][cb] = __builtin_amdgcn_mfma_f32_16x16x32_bf16(afr[rb], bfr[cb], acc[rb][cb], 0, 0, 0);
        }
    }

    // relu + rowsum + normalize (x0.7) -> bf16 attn
    float rs[2][4];
    #pragma unroll
    for (int rb = 0; rb < 2; ++rb)
        #pragma unroll
        for (int r = 0; r < 4; ++r) {
            float s = 0.f;
            #pragma unroll
            for (int cb = 0; cb < 4; ++cb) {
                float v = fmaxf(acc[rb][cb][r], 0.0f);
                acc[rb][cb][r] = v;
                s += v;
            }
            rs[rb][r] = s;
        }
    #pragma unroll
    for (int m = 1; m < 16; m <<= 1)
        #pragma unroll
        for (int rb = 0; rb < 2; ++rb)
            #pragma unroll
            for (int r = 0; r < 4; ++r)
                rs[rb][r] += __shfl_xor(rs[rb][r], m, 64);
    if (m16 == 0) {
        #pragma unroll
        for (int rb = 0; rb < 2; ++rb)
            #pragma unroll
            for (int r = 0; r < 4; ++r)
                rsum[wave][(rb << 4) + (quad << 2) + r] = rs[rb][r];
    }
    __syncthreads();

    unsigned short* outb = attn + ((size_t)tbl << 16);
    #pragma unroll
    for (int rb = 0; rb < 2; ++rb) {
        #pragma unroll
        for (int r = 0; r < 4; ++r) {
            int row = (rb << 4) + (quad << 2) + r;
            float tot = rsum[0][row] + rsum[1][row] + rsum[2][row] + rsum[3][row];
            float inv = (1.0f - SKIPF) / (tot + 16.0f * EPSF);
            #pragma unroll
            for (int cb = 0; cb < 4; ++cb) {
                int col = (wave << 6) + (cb << 4) + m16;
                outb[((size_t)(n0 + row) << 8) + col] = f2bf(acc[rb][cb][r] * inv);
            }
        }
    }
}

// ---------------------------------------------------------------------------
// scan: A_t = 0.3*A_{t-1} + attn_t (attn pre-scaled by 0.7), in place over t.
// grid = 2048 x 256, 4 elems/thread.
// ---------------------------------------------------------------------------
__global__ __launch_bounds__(256) void k_scan(const float* __restrict__ supports,
                                              unsigned short* __restrict__ AttA) {
    size_t flat = ((size_t)blockIdx.x * 256 + threadIdx.x) * 4;
    float4 s4 = *(const float4*)(supports + flat);
    float a0 = s4.x, a1 = s4.y, a2 = s4.z, a3 = s4.w;
    #pragma unroll
    for (int t = 0; t < TT; ++t) {
        unsigned short* p = AttA + ((size_t)t << 21) + flat;
        uint2 u = *(uint2*)p;
        a0 = SKIPF * a0 + bf2f((unsigned short)(u.x & 0xffff));
        a1 = SKIPF * a1 + bf2f((unsigned short)(u.x >> 16));
        a2 = SKIPF * a2 + bf2f((unsigned short)(u.y & 0xffff));
        a3 = SKIPF * a3 + bf2f((unsigned short)(u.y >> 16));
        uint2 o;
        o.x = pack2(f2bf(a0), f2bf(a1));
        o.y = pack2(f2bf(a2), f2bf(a3));
        *(uint2*)p = o;
    }
}

// ---------------------------------------------------------------------------
// hTinit: hT0[tb][d][n] = bf16(x[tb][n][d]) for all 512 tb. grid 512*32.
// ---------------------------------------------------------------------------
__global__ __launch_bounds__(256) void k_hTinit(const float* __restrict__ x,
                                                unsigned short* __restrict__ hT) {
    int bid = blockIdx.x;
    int tb = bid >> 5; int r = bid & 31; int d0 = (r >> 3) << 5; int n0 = (r & 7) << 5;
    __shared__ float tl[32][33];
    int tid = threadIdx.x;
    int i = tid >> 5, j = tid & 31;
    #pragma unroll
    for (int s = 0; s < 4; ++s) {
        int nl = (s << 3) + i;
        tl[nl][j] = x[((size_t)(tb * 256 + n0 + nl) << 7) + d0 + j];
    }
    __syncthreads();
    #pragma unroll
    for (int s = 0; s < 4; ++s) {
        int dd = (s << 3) + i;
        hT[((size_t)(tb * 128 + d0 + dd) << 8) + n0 + j] = f2bf(tl[j][dd]);
    }
}

// ---------------------------------------------------------------------------
// wprep: bf16-transposed weights WT[dout][k]
// ---------------------------------------------------------------------------
__global__ __launch_bounds__(256) void k_wprep(const float* __restrict__ Wa,
                                               const float* __restrict__ Wr,
                                               const float* __restrict__ Wz,
                                               const float* __restrict__ Wh,
                                               unsigned short* __restrict__ WaT,
                                               unsigned short* __restrict__ WrT,
                                               unsigned short* __restrict__ WzT,
                                               unsigned short* __restrict__ WhT) {
    int idx = blockIdx.x * 256 + threadIdx.x;     // 0..32767
    if (idx < 16384) {
        int dout = idx >> 7, din = idx & 127;
        WaT[idx] = f2bf(Wa[(din << 7) + dout]);
    }
    {
        int dout = idx >> 8, dk = idx & 255;
        WrT[idx] = f2bf(Wr[(dk << 7) + dout]);
        WzT[idx] = f2bf(Wz[(dk << 7) + dout]);
        WhT[idx] = f2bf(Wh[(dk << 7) + dout]);
    }
}

// ---------------------------------------------------------------------------
// step: fused GGNN/GRU step, batched over tb = t*32+b (512), 32-row tiles.
// h state lives ONLY in hT (bf16, [tb][d][n]). grid = 8 rg x 512 tb = 4096.
// ---------------------------------------------------------------------------
__global__ __launch_bounds__(256) void k_step(
    const unsigned short* __restrict__ AttA,
    const unsigned short* __restrict__ hT,
    const unsigned short* __restrict__ WaT, const float* __restrict__ ba,
    const unsigned short* __restrict__ WrT, const float* __restrict__ br,
    const unsigned short* __restrict__ WzT, const float* __restrict__ bz,
    const unsigned short* __restrict__ WhT, const float* __restrict__ bh,
    unsigned short* __restrict__ hT_o) {

    int bid = blockIdx.x;
    int tb = bid & 511, rg = bid >> 9;
    int n0 = rg << 5;
    int tid = threadIdx.x;
    int wave = tid >> 6, lane = tid & 63;
    int m16 = lane & 15, quad = lane >> 4;
    int wcol = wave << 5;

    __shared__ unsigned short msgS[32 * 136];
    __shared__ unsigned short ahS[32 * 264];   // k 0..127 = a, 128..255 = h (later r*h)

    const unsigned short* hTb = hT + ((size_t)tb << 15);

    // stage h-half of ahS from hT (transpose: ahS[row][128+d] = hT[d][n0+row])
    #pragma unroll
    for (int j = 0; j < 16; ++j) {
        int idx = (j << 8) + tid;            // 0..4095
        int d = idx >> 5, row = idx & 31;
        ahS[row * 264 + 128 + d] = hTb[((size_t)d << 8) + n0 + row];
    }

    // ---- bmm: msg = A_tile @ h  (K=256) ----
    f32x4 acc[2][2];
    #pragma unroll
    for (int rb = 0; rb < 2; ++rb)
        #pragma unroll
        for (int cb = 0; cb < 2; ++cb) acc[rb][cb] = (f32x4){0.f, 0.f, 0.f, 0.f};

    const unsigned short* Ab = AttA + ((size_t)tb << 16) + ((size_t)n0 << 8);
    #pragma unroll 2
    for (int ks = 0; ks < 8; ++ks) {
        bf16x8 af[2], bf[2];
        #pragma unroll
        for (int rb = 0; rb < 2; ++rb)
            af[rb] = *(const bf16x8*)(Ab + (((rb << 4) + m16) << 8) + (ks << 5) + (quad << 3));
        #pragma unroll
        for (int cb = 0; cb < 2; ++cb)
            bf[cb] = *(const bf16x8*)(hTb + ((wcol + (cb << 4) + m16) << 8) + (ks << 5) + (quad << 3));
        #pragma unroll
        for (int rb = 0; rb < 2; ++rb)
            #pragma unroll
            for (int cb = 0; cb < 2; ++cb)
                acc[rb][cb] = __builtin_amdgcn_mfma_f32_16x16x32_bf16(af[rb], bf[cb], acc[rb][cb], 0, 0, 0);
    }
    #pragma unroll
    for (int rb = 0; rb < 2; ++rb)
        #pragma unroll
        for (int cb = 0; cb < 2; ++cb)
            #pragma unroll
            for (int r = 0; r < 4; ++r)
                msgS[((rb << 4) + (quad << 2) + r) * 136 + wcol + (cb << 4) + m16] = f2bf(acc[rb][cb][r]);
    __syncthreads();   // covers h-half staging too

    // ---- a = msg @ Wa + ba ----
    #pragma unroll
    for (int rb = 0; rb < 2; ++rb)
        #pragma unroll
        for (int cb = 0; cb < 2; ++cb) acc[rb][cb] = (f32x4){0.f, 0.f, 0.f, 0.f};
    #pragma unroll
    for (int ks = 0; ks < 4; ++ks) {
        bf16x8 af[2], bf[2];
        #pragma unroll
        for (int rb = 0; rb < 2; ++rb)
            af[rb] = *(const bf16x8*)(msgS + ((rb << 4) + m16) * 136 + (ks << 5) + (quad << 3));
        #pragma unroll
        for (int cb = 0; cb < 2; ++cb)
            bf[cb] = *(const bf16x8*)(WaT + ((wcol + (cb << 4) + m16) << 7) + (ks << 5) + (quad << 3));
        #pragma unroll
        for (int rb = 0; rb < 2; ++rb)
            #pragma unroll
            for (int cb = 0; cb < 2; ++cb)
                acc[rb][cb] = __builtin_amdgcn_mfma_f32_16x16x32_bf16(af[rb], bf[cb], acc[rb][cb], 0, 0, 0);
    }
    {
        float bav[2];
        #pragma unroll
        for (int cb = 0; cb < 2; ++cb) bav[cb] = ba[wcol + (cb << 4) + m16];
        #pragma unroll
        for (int rb = 0; rb < 2; ++rb)
            #pragma unroll
            for (int cb = 0; cb < 2; ++cb)
                #pragma unroll
                for (int r = 0; r < 4; ++r)
                    ahS[((rb << 4) + (quad << 2) + r) * 264 + wcol + (cb << 4) + m16] =
                        f2bf(acc[rb][cb][r] + bav[cb]);
    }
    __syncthreads();

    // h_old (for r*h and final update): uint2 = 4 consecutive n at fixed col
    float hv[2][2][4];
    #pragma unroll
    for (int rb = 0; rb < 2; ++rb)
        #pragma unroll
        for (int cb = 0; cb < 2; ++cb) {
            int col = wcol + (cb << 4) + m16;
            uint2 u = *(const uint2*)(hTb + ((size_t)col << 8) + n0 + (rb << 4) + (quad << 2));
            hv[rb][cb][0] = bf2f((unsigned short)(u.x & 0xffff));
            hv[rb][cb][1] = bf2f((unsigned short)(u.x >> 16));
            hv[rb][cb][2] = bf2f((unsigned short)(u.y & 0xffff));
            hv[rb][cb][3] = bf2f((unsigned short)(u.y >> 16));
        }

    // ---- r and z ----
    f32x4 racc[2][2], zacc[2][2];
    #pragma unroll
    for (int rb = 0; rb < 2; ++rb)
        #pragma unroll
        for (int cb = 0; cb < 2; ++cb) {
            racc[rb][cb] = (f32x4){0.f, 0.f, 0.f, 0.f};
            zacc[rb][cb] = (f32x4){0.f, 0.f, 0.f, 0.f};
        }
    #pragma unroll 2
    for (int ks = 0; ks < 8; ++ks) {
        bf16x8 af[2], bfr[2], bfz[2];
        #pragma unroll
        for (int rb = 0; rb < 2; ++rb)
            af[rb] = *(const bf16x8*)(ahS + ((rb << 4) + m16) * 264 + (ks << 5) + (quad << 3));
        #pragma unroll
        for (int cb = 0; cb < 2; ++cb) {
            int dout = wcol + (cb << 4) + m16;
            bfr[cb] = *(const bf16x8*)(WrT + (dout << 8) + (ks << 5) + (quad << 3));
            bfz[cb] = *(const bf16x8*)(WzT + (dout << 8) + (ks << 5) + (quad << 3));
        }
        #pragma unroll
        for (int rb = 0; rb < 2; ++rb)
            #pragma unroll
            for (int cb = 0; cb < 2; ++cb) {
                racc[rb][cb] = __builtin_amdgcn_mfma_f32_16x16x32_bf16(af[rb], bfr[cb], racc[rb][cb], 0, 0, 0);
                zacc[rb][cb] = __builtin_amdgcn_mfma_f32_16x16x32_bf16(af[rb], bfz[cb], zacc[rb][cb], 0, 0, 0);
            }
    }
    float zv[2][2][4];
    {
        float brv[2], bzv[2];
        #pragma unroll
        for (int cb = 0; cb < 2; ++cb) {
            brv[cb] = br[wcol + (cb << 4) + m16];
            bzv[cb] = bz[wcol + (cb << 4) + m16];
        }
        #pragma unroll
        for (int rb = 0; rb < 2; ++rb)
            #pragma unroll
            for (int cb = 0; cb < 2; ++cb)
                #pragma unroll
                for (int r = 0; r < 4; ++r) {
                    racc[rb][cb][r] = sigmoidf_(racc[rb][cb][r] + brv[cb]);
                    zv[rb][cb][r]  = sigmoidf_(zacc[rb][cb][r] + bzv[cb]);
                }
    }
    __syncthreads();   // all ahS reads done -> safe to overwrite h-half

    #pragma unroll
    for (int rb = 0; rb < 2; ++rb)
        #pragma unroll
        for (int cb = 0; cb < 2; ++cb)
            #pragma unroll
            for (int r = 0; r < 4; ++r)
                ahS[((rb << 4) + (quad << 2) + r) * 264 + 128 + wcol + (cb << 4) + m16] =
                    f2bf(racc[rb][cb][r] * hv[rb][cb][r]);
    __syncthreads();

    // ---- h_tilde ----
    #pragma unroll
    for (int rb = 0; rb < 2; ++rb)
        #pragma unroll
        for (int cb = 0; cb < 2; ++cb) acc[rb][cb] = (f32x4){0.f, 0.f, 0.f, 0.f};
    #pragma unroll 2
    for (int ks = 0; ks < 8; ++ks) {
        bf16x8 af[2], bf[2];
        #pragma unroll
        for (int rb = 0; rb < 2; ++rb)
            af[rb] = *(const bf16x8*)(ahS + ((rb << 4) + m16) * 264 + (ks << 5) + (quad << 3));
        #pragma unroll
        for (int cb = 0; cb < 2; ++cb)
            bf[cb] = *(const bf16x8*)(WhT + ((wcol + (cb << 4) + m16) << 8) + (ks << 5) + (quad << 3));
        #pragma unroll
        for (int rb = 0; rb < 2; ++rb)
            #pragma unroll
            for (int cb = 0; cb < 2; ++cb)
                acc[rb][cb] = __builtin_amdgcn_mfma_f32_16x16x32_bf16(af[rb], bf[cb], acc[rb][cb], 0, 0, 0);
    }

    // ---- update + writes (hT only) ----
    {
        float bhv[2];
        #pragma unroll
        for (int cb = 0; cb < 2; ++cb) bhv[cb] = bh[wcol + (cb << 4) + m16];
        #pragma unroll
        for (int rb = 0; rb < 2; ++rb)
            #pragma unroll
            for (int cb = 0; cb < 2; ++cb) {
                int col = wcol + (cb << 4) + m16;
                unsigned short pk[4];
                #pragma unroll
                for (int r = 0; r < 4; ++r) {
                    float ht = tanhf_(acc[rb][cb][r] + bhv[cb]);
                    float hn = hv[rb][cb][r] + zv[rb][cb][r] * (ht - hv[rb][cb][r]);
                    pk[r] = f2bf(hn);
                }
                uint2 p;
                p.x = pack2(pk[0], pk[1]); p.y = pack2(pk[2], pk[3]);
                *(uint2*)(hT_o + ((size_t)(tb * 128 + col) << 8) + n0 + (rb << 4) + (quad << 2)) = p;
            }
    }
}

// ---------------------------------------------------------------------------
// fc: logits[b,c] = sum over col-major h (hT, t=15) + bfc. grid = 512.
// ---------------------------------------------------------------------------
__global__ __launch_bounds__(256) void k_fc(const unsigned short* __restrict__ hT,
                                            const float* __restrict__ Wfc,
                                            const float* __restrict__ bfc,
                                            float* __restrict__ out) {
    int bid = blockIdx.x;
    int b = bid >> 4, part = bid & 15;
    int tid = threadIdx.x;
    int tb = 15 * 32 + b;
    const unsigned short* hp = hT + ((size_t)tb << 15);
    int i = part * 2048 + tid * 8;       // linear col-major: i = d*256 + n
    int d = i >> 8, n = i & 255;
    uint4 hu = *(const uint4*)(hp + i);
    unsigned short hs[8];
    hs[0] = hu.x & 0xffff; hs[1] = hu.x >> 16;
    hs[2] = hu.y & 0xffff; hs[3] = hu.y >> 16;
    hs[4] = hu.z & 0xffff; hs[5] = hu.z >> 16;
    hs[6] = hu.w & 0xffff; hs[7] = hu.w >> 16;
    float a0 = 0.f, a1 = 0.f;
    #pragma unroll
    for (int k = 0; k < 8; ++k) {
        float v = bf2f(hs[k]);
        const float2 w = *(const float2*)(Wfc + ((size_t)(n + k) * 128 + d) * 2);
        a0 = fmaf(v, w.x, a0);
        a1 = fmaf(v, w.y, a1);
    }
    int wave = tid >> 6, lane = tid & 63;
    #pragma unroll
    for (int off = 32; off; off >>= 1) {
        a0 += __shfl_down(a0, off, 64);
        a1 += __shfl_down(a1, off, 64);
    }
    __shared__ float r0[4], r1[4];
    if (lane == 0) { r0[wave] = a0; r1[wave] = a1; }
    __syncthreads();
    if (tid == 0) {
        float s0 = r0[0] + r0[1] + r0[2] + r0[3];
        float s1 = r1[0] + r1[1] + r1[2] + r1[3];
        if (part == 0) { s0 += bfc[0]; s1 += bfc[1]; }
        atomicAdd(&out[b * 2 + 0], s0);
        atomicAdd(&out[b * 2 + 1], s1);
    }
}

// ---------------------------------------------------------------------------
extern "C" void kernel_launch(void* const* d_in, const int* in_sizes, int n_in,
                              void* d_out, int out_size, void* d_ws, size_t ws_size,
                              hipStream_t stream) {
    const float* x_all    = (const float*)d_in[0];
    const float* supports = (const float*)d_in[1];
    const float* Wgl = (const float*)d_in[2];
    const float* Wa  = (const float*)d_in[3];
    const float* ba  = (const float*)d_in[4];
    const float* Wr  = (const float*)d_in[5];
    const float* br  = (const float*)d_in[6];
    const float* Wz  = (const float*)d_in[7];
    const float* bz  = (const float*)d_in[8];
    const float* Wh  = (const float*)d_in[9];
    const float* bh  = (const float*)d_in[10];
    const float* Wfc = (const float*)d_in[11];
    const float* bfc = (const float*)d_in[12];
    float* out = (float*)d_out;

    char* p = (char*)d_ws;
    auto alloc = [&](size_t bytes) { char* r = p; p += (bytes + 255) & ~(size_t)255; return r; };

    unsigned short* AttA = (unsigned short*)alloc((size_t)TT * BB * NN * NN * 2);  // 64 MB
    unsigned short* hT0  = (unsigned short*)alloc((size_t)TT * BB * DD * NN * 2);  // 32 MB
    unsigned short* hT1  = (unsigned short*)alloc((size_t)TT * BB * DD * NN * 2);  // 32 MB
    unsigned short* WaT  = (unsigned short*)alloc(128 * 128 * 2);
    unsigned short* WrT  = (unsigned short*)alloc(256 * 128 * 2);
    unsigned short* WzT  = (unsigned short*)alloc(256 * 128 * 2);
    unsigned short* WhT  = (unsigned short*)alloc(256 * 128 * 2);
    // total ~128.2 MB  (<= ws budget; see note at top)

    // V (per t-group, GT*32*256*2048 bf16 = 64 MB) aliases hT0+hT1:
    // all gram work finishes before any hT buffer is written.
    unsigned short* V = hT0;

    k_wprep<<<128, 256, 0, stream>>>(Wa, Wr, Wz, Wh, WaT, WrT, WzT, WhT);

    for (int g = 0; g < TT / GT; ++g) {
        const float* xg = x_all + (size_t)g * GT * BB * NN * DD;
        k_buildV<<<GT * BB * NN, 128, 0, stream>>>(xg, Wgl, V);
        k_gram<<<8 * GT * BB, 256, 0, stream>>>(V, AttA + (size_t)g * GT * BB * NN * NN);
    }
    k_scan<<<2048, 256, 0, stream>>>(supports, AttA);
    k_hTinit<<<TT * BB * 32, 256, 0, stream>>>(x_all, hT0);

    const unsigned short* hT_in = hT0;
    for (int s = 0; s < NSTEPS; ++s) {
        unsigned short* hTo = (s & 1) ? hT0 : hT1;
        k_step<<<8 * 512, 256, 0, stream>>>(AttA, hT_in,
                                            WaT, ba, WrT, br, WzT, bz, WhT, bh,
                                            hTo);
        hT_in = hTo;
    }
    // after 5 steps (s=4) final h is in hT1
    hipMemsetAsync(d_out, 0, (size_t)out_size * sizeof(float), stream);
    k_fc<<<BB * 16, 256, 0, stream>>>(hT1, Wfc, bfc, out);
}

// Round 6
// 1653.281 us; speedup vs baseline: 2.1324x; 1.2010x over previous
//
#include <hip/hip_runtime.h>
#include <math.h>

#define TT 16
#define BB 32
#define NN 256
#define DD 128
#define NSTEPS 5
#define SKIPF 0.3f
#define EPSF 1e-8f
#define GT 2            // t-group size for V materialization (V aliases hT0+hT1)

// Workspace budget: ws_size < 192.4 MB (round-4 overflow evidence). This
// version uses 64 (AttA) + 32 (hT0) + 32 (hT1) + ~0.22 MB = ~128.2 MB.
// V (64 MB, GT=2) aliases hT0+hT1 (written only after all gram work).

typedef __attribute__((ext_vector_type(8))) short bf16x8;
typedef __attribute__((ext_vector_type(4))) float f32x4;

__device__ __forceinline__ unsigned short f2bf(float f) {
    union { float f; unsigned u; } v; v.f = f;
    unsigned r = (v.u + 0x7FFF + ((v.u >> 16) & 1)) >> 16;
    return (unsigned short)r;
}
__device__ __forceinline__ float bf2f(unsigned short u) {
    union { unsigned u; float f; } v; v.u = ((unsigned)u) << 16; return v.f;
}
__device__ __forceinline__ unsigned pack2(unsigned short a, unsigned short b) {
    return (unsigned)a | ((unsigned)b << 16);
}
__device__ __forceinline__ float sigmoidf_(float x) {
    return 1.0f / (1.0f + __expf(-x));
}
__device__ __forceinline__ float tanhf_(float x) {
    return 1.0f - 2.0f / (__expf(2.0f * x) + 1.0f);
}
// async global->LDS, 16B per lane; lds base must be wave-uniform
__device__ __forceinline__ void gload16(const void* g, void* l) {
    __builtin_amdgcn_global_load_lds(
        (const __attribute__((address_space(1))) unsigned int*)g,
        (__attribute__((address_space(3))) unsigned int*)l, 16, 0, 0);
}

// ---------------------------------------------------------------------------
// buildV (per t-group): V[tbl,n,h*128+d] = bf16( x*Wgl[h]/(||x*w_h||+eps) )
// grid = GT*32*256 blocks x 128 threads; x pre-offset to group start
// ---------------------------------------------------------------------------
__global__ __launch_bounds__(128) void k_buildV(const float* __restrict__ x,
                                                const float* __restrict__ Wgl,
                                                unsigned short* __restrict__ V) {
    int bid = blockIdx.x;
    int tbl = bid >> 8, n = bid & 255;
    int d = threadIdx.x;
    __shared__ float part[16][2];
    float xv = x[((size_t)(tbl * 256 + n) << 7) + d];
    float vv[16];
    int wave = d >> 6, lane = d & 63;
    #pragma unroll
    for (int h = 0; h < 16; ++h) {
        float v = xv * Wgl[(h << 7) + d];
        vv[h] = v;
        float s = v * v;
        #pragma unroll
        for (int off = 32; off; off >>= 1) s += __shfl_down(s, off, 64);
        if (lane == 0) part[h][wave] = s;
    }
    __syncthreads();
    unsigned short* Vr = V + ((size_t)(tbl * 256 + n) << 11);
    #pragma unroll
    for (int h = 0; h < 16; ++h) {
        float inv = 1.0f / (sqrtf(part[h][0] + part[h][1]) + EPSF);
        Vr[(h << 7) + d] = f2bf(vv[h] * inv);
    }
}

// ---------------------------------------------------------------------------
// gram (per t-group): attn = 0.7 * rownorm(relu(V V^T))  -> bf16
// grid = 8 rg x (GT*32) tbl = 512 blocks, 256 threads, 64.5 KB LDS (2/CU).
// m97-style: async global_load_lds(16B) staging, k-chunk 128, XOR-16 swizzle
// (LDS slot (row,g) holds global group g^(row&15); frag reads apply same XOR
//  -> 2-way bank aliasing = free; no padding needed so DMA layout works).
// ---------------------------------------------------------------------------
__global__ __launch_bounds__(256) void k_gram(const unsigned short* __restrict__ V,
                                              unsigned short* __restrict__ attn) {
    int bid = blockIdx.x;
    int tbl = bid & (GT * 32 - 1);
    int rg  = bid / (GT * 32);          // 0..7
    int n0 = rg << 5;
    int tid = threadIdx.x;
    int wave = tid >> 6, lane = tid & 63;
    int m16 = lane & 15, quad = lane >> 4;

    __shared__ unsigned short Vs[256 * 128];   // 64 KB chunk (256 rows x 128 k)
    __shared__ float rsum[4][32];

    f32x4 acc[2][4];
    #pragma unroll
    for (int rb = 0; rb < 2; ++rb)
        #pragma unroll
        for (int cb = 0; cb < 4; ++cb) acc[rb][cb] = (f32x4){0.f, 0.f, 0.f, 0.f};

    const unsigned short* Vb = V + ((size_t)tbl << 19);   // tbl*256*2048
    const char* Vsb = (const char*)Vs;

    // lane-constant pieces for staging
    int lrow_off = lane >> 4;          // 0..3 row within 4-row group
    int gslot = lane & 15;             // destination 16B slot

    for (int kc = 0; kc < 16; ++kc) {
        // ---- stage chunk kc: 256 rows x 128 k (64 KB) via async DMA ----
        #pragma unroll
        for (int j = 0; j < 16; ++j) {
            int r0 = (wave << 6) + (j << 2);          // wave-uniform
            int grow = r0 + lrow_off;
            int gsw = gslot ^ (grow & 15);            // source group (swizzled)
            const unsigned short* src = Vb + ((size_t)grow << 11) + (kc << 7) + (gsw << 3);
            gload16(src, Vs + (r0 << 7));
        }
        __syncthreads();   // drains vmcnt(0) before barrier

        // ---- 32 MFMAs per wave over this 128-k chunk ----
        #pragma unroll
        for (int ks = 0; ks < 4; ++ks) {
            int sw = (((ks << 2) | quad) ^ m16) << 4;   // byte offset of 16B group
            bf16x8 afr[2], bfr[4];
            #pragma unroll
            for (int rb = 0; rb < 2; ++rb) {
                int rr = n0 + (rb << 4) + m16;
                afr[rb] = *(const bf16x8*)(Vsb + (rr << 8) + sw);
            }
            #pragma unroll
            for (int cb = 0; cb < 4; ++cb) {
                int cc = (wave << 6) + (cb << 4) + m16;
                bfr[cb] = *(const bf16x8*)(Vsb + (cc << 8) + sw);
            }
            #pragma unroll
            for (int rb = 0; rb < 2; ++rb)
                #pragma unroll
                for (int cb = 0; cb < 4; ++cb)
                    acc[rb][cb] = __builtin_amdgcn_mfma_f32_16x16x32_bf16(afr[rb], bfr[cb], acc[rb][cb], 0, 0, 0);
        }
        __syncthreads();
    }

    // relu + rowsum + normalize (x0.7) -> bf16 attn
    float rs[2][4];
    #pragma unroll
    for (int rb = 0; rb < 2; ++rb)
        #pragma unroll
        for (int r = 0; r < 4; ++r) {
            float s = 0.f;
            #pragma unroll
            for (int cb = 0; cb < 4; ++cb) {
                float v = fmaxf(acc[rb][cb][r], 0.0f);
                acc[rb][cb][r] = v;
                s += v;
            }
            rs[rb][r] = s;
        }
    #pragma unroll
    for (int m = 1; m < 16; m <<= 1)
        #pragma unroll
        for (int rb = 0; rb < 2; ++rb)
            #pragma unroll
            for (int r = 0; r < 4; ++r)
                rs[rb][r] += __shfl_xor(rs[rb][r], m, 64);
    if (m16 == 0) {
        #pragma unroll
        for (int rb = 0; rb < 2; ++rb)
            #pragma unroll
            for (int r = 0; r < 4; ++r)
                rsum[wave][(rb << 4) + (quad << 2) + r] = rs[rb][r];
    }
    __syncthreads();

    unsigned short* outb = attn + ((size_t)tbl << 16);
    #pragma unroll
    for (int rb = 0; rb < 2; ++rb) {
        #pragma unroll
        for (int r = 0; r < 4; ++r) {
            int row = (rb << 4) + (quad << 2) + r;
            float tot = rsum[0][row] + rsum[1][row] + rsum[2][row] + rsum[3][row];
            float inv = (1.0f - SKIPF) / (tot + 16.0f * EPSF);
            #pragma unroll
            for (int cb = 0; cb < 4; ++cb) {
                int col = (wave << 6) + (cb << 4) + m16;
                outb[((size_t)(n0 + row) << 8) + col] = f2bf(acc[rb][cb][r] * inv);
            }
        }
    }
}

// ---------------------------------------------------------------------------
// scan: A_t = 0.3*A_{t-1} + attn_t (attn pre-scaled by 0.7), in place over t.
// grid = 2048 x 256, 4 elems/thread.
// ---------------------------------------------------------------------------
__global__ __launch_bounds__(256) void k_scan(const float* __restrict__ supports,
                                              unsigned short* __restrict__ AttA) {
    size_t flat = ((size_t)blockIdx.x * 256 + threadIdx.x) * 4;
    float4 s4 = *(const float4*)(supports + flat);
    float a0 = s4.x, a1 = s4.y, a2 = s4.z, a3 = s4.w;
    #pragma unroll
    for (int t = 0; t < TT; ++t) {
        unsigned short* p = AttA + ((size_t)t << 21) + flat;
        uint2 u = *(uint2*)p;
        a0 = SKIPF * a0 + bf2f((unsigned short)(u.x & 0xffff));
        a1 = SKIPF * a1 + bf2f((unsigned short)(u.x >> 16));
        a2 = SKIPF * a2 + bf2f((unsigned short)(u.y & 0xffff));
        a3 = SKIPF * a3 + bf2f((unsigned short)(u.y >> 16));
        uint2 o;
        o.x = pack2(f2bf(a0), f2bf(a1));
        o.y = pack2(f2bf(a2), f2bf(a3));
        *(uint2*)p = o;
    }
}

// ---------------------------------------------------------------------------
// hTinit: hT0[tb][d][n] = bf16(x[tb][n][d]) for all 512 tb. grid 512*32.
// ---------------------------------------------------------------------------
__global__ __launch_bounds__(256) void k_hTinit(const float* __restrict__ x,
                                                unsigned short* __restrict__ hT) {
    int bid = blockIdx.x;
    int tb = bid >> 5; int r = bid & 31; int d0 = (r >> 3) << 5; int n0 = (r & 7) << 5;
    __shared__ float tl[32][33];
    int tid = threadIdx.x;
    int i = tid >> 5, j = tid & 31;
    #pragma unroll
    for (int s = 0; s < 4; ++s) {
        int nl = (s << 3) + i;
        tl[nl][j] = x[((size_t)(tb * 256 + n0 + nl) << 7) + d0 + j];
    }
    __syncthreads();
    #pragma unroll
    for (int s = 0; s < 4; ++s) {
        int dd = (s << 3) + i;
        hT[((size_t)(tb * 128 + d0 + dd) << 8) + n0 + j] = f2bf(tl[j][dd]);
    }
}

// ---------------------------------------------------------------------------
// wprep: bf16-transposed weights WT[dout][k]
// ---------------------------------------------------------------------------
__global__ __launch_bounds__(256) void k_wprep(const float* __restrict__ Wa,
                                               const float* __restrict__ Wr,
                                               const float* __restrict__ Wz,
                                               const float* __restrict__ Wh,
                                               unsigned short* __restrict__ WaT,
                                               unsigned short* __restrict__ WrT,
                                               unsigned short* __restrict__ WzT,
                                               unsigned short* __restrict__ WhT) {
    int idx = blockIdx.x * 256 + threadIdx.x;     // 0..32767
    if (idx < 16384) {
        int dout = idx >> 7, din = idx & 127;
        WaT[idx] = f2bf(Wa[(din << 7) + dout]);
    }
    {
        int dout = idx >> 8, dk = idx & 255;
        WrT[idx] = f2bf(Wr[(dk << 7) + dout]);
        WzT[idx] = f2bf(Wz[(dk << 7) + dout]);
        WhT[idx] = f2bf(Wh[(dk << 7) + dout]);
    }
}

// ---------------------------------------------------------------------------
// step: fused GGNN/GRU step, batched over tb = t*32+b (512), 32-row tiles.
// h state lives ONLY in hT (bf16, [tb][d][n]). grid = 8 rg x 512 tb = 4096.
// ---------------------------------------------------------------------------
__global__ __launch_bounds__(256) void k_step(
    const unsigned short* __restrict__ AttA,
    const unsigned short* __restrict__ hT,
    const unsigned short* __restrict__ WaT, const float* __restrict__ ba,
    const unsigned short* __restrict__ WrT, const float* __restrict__ br,
    const unsigned short* __restrict__ WzT, const float* __restrict__ bz,
    const unsigned short* __restrict__ WhT, const float* __restrict__ bh,
    unsigned short* __restrict__ hT_o) {

    int bid = blockIdx.x;
    int tb = bid & 511, rg = bid >> 9;
    int n0 = rg << 5;
    int tid = threadIdx.x;
    int wave = tid >> 6, lane = tid & 63;
    int m16 = lane & 15, quad = lane >> 4;
    int wcol = wave << 5;

    __shared__ unsigned short msgS[32 * 136];
    __shared__ unsigned short ahS[32 * 264];   // k 0..127 = a, 128..255 = h (later r*h)

    const unsigned short* hTb = hT + ((size_t)tb << 15);

    // stage h-half of ahS from hT (transpose: ahS[row][128+d] = hT[d][n0+row])
    #pragma unroll
    for (int j = 0; j < 16; ++j) {
        int idx = (j << 8) + tid;            // 0..4095
        int d = idx >> 5, row = idx & 31;
        ahS[row * 264 + 128 + d] = hTb[((size_t)d << 8) + n0 + row];
    }

    // ---- bmm: msg = A_tile @ h  (K=256) ----
    f32x4 acc[2][2];
    #pragma unroll
    for (int rb = 0; rb < 2; ++rb)
        #pragma unroll
        for (int cb = 0; cb < 2; ++cb) acc[rb][cb] = (f32x4){0.f, 0.f, 0.f, 0.f};

    const unsigned short* Ab = AttA + ((size_t)tb << 16) + ((size_t)n0 << 8);
    #pragma unroll 2
    for (int ks = 0; ks < 8; ++ks) {
        bf16x8 af[2], bf[2];
        #pragma unroll
        for (int rb = 0; rb < 2; ++rb)
            af[rb] = *(const bf16x8*)(Ab + (((rb << 4) + m16) << 8) + (ks << 5) + (quad << 3));
        #pragma unroll
        for (int cb = 0; cb < 2; ++cb)
            bf[cb] = *(const bf16x8*)(hTb + ((wcol + (cb << 4) + m16) << 8) + (ks << 5) + (quad << 3));
        #pragma unroll
        for (int rb = 0; rb < 2; ++rb)
            #pragma unroll
            for (int cb = 0; cb < 2; ++cb)
                acc[rb][cb] = __builtin_amdgcn_mfma_f32_16x16x32_bf16(af[rb], bf[cb], acc[rb][cb], 0, 0, 0);
    }
    #pragma unroll
    for (int rb = 0; rb < 2; ++rb)
        #pragma unroll
        for (int cb = 0; cb < 2; ++cb)
            #pragma unroll
            for (int r = 0; r < 4; ++r)
                msgS[((rb << 4) + (quad << 2) + r) * 136 + wcol + (cb << 4) + m16] = f2bf(acc[rb][cb][r]);
    __syncthreads();   // covers h-half staging too

    // ---- a = msg @ Wa + ba ----
    #pragma unroll
    for (int rb = 0; rb < 2; ++rb)
        #pragma unroll
        for (int cb = 0; cb < 2; ++cb) acc[rb][cb] = (f32x4){0.f, 0.f, 0.f, 0.f};
    #pragma unroll
    for (int ks = 0; ks < 4; ++ks) {
        bf16x8 af[2], bf[2];
        #pragma unroll
        for (int rb = 0; rb < 2; ++rb)
            af[rb] = *(const bf16x8*)(msgS + ((rb << 4) + m16) * 136 + (ks << 5) + (quad << 3));
        #pragma unroll
        for (int cb = 0; cb < 2; ++cb)
            bf[cb] = *(const bf16x8*)(WaT + ((wcol + (cb << 4) + m16) << 7) + (ks << 5) + (quad << 3));
        #pragma unroll
        for (int rb = 0; rb < 2; ++rb)
            #pragma unroll
            for (int cb = 0; cb < 2; ++cb)
                acc[rb][cb] = __builtin_amdgcn_mfma_f32_16x16x32_bf16(af[rb], bf[cb], acc[rb][cb], 0, 0, 0);
    }
    {
        float bav[2];
        #pragma unroll
        for (int cb = 0; cb < 2; ++cb) bav[cb] = ba[wcol + (cb << 4) + m16];
        #pragma unroll
        for (int rb = 0; rb < 2; ++rb)
            #pragma unroll
            for (int cb = 0; cb < 2; ++cb)
                #pragma unroll
                for (int r = 0; r < 4; ++r)
                    ahS[((rb << 4) + (quad << 2) + r) * 264 + wcol + (cb << 4) + m16] =
                        f2bf(acc[rb][cb][r] + bav[cb]);
    }
    __syncthreads();

    // h_old (for r*h and final update): uint2 = 4 consecutive n at fixed col
    float hv[2][2][4];
    #pragma unroll
    for (int rb = 0; rb < 2; ++rb)
        #pragma unroll
        for (int cb = 0; cb < 2; ++cb) {
            int col = wcol + (cb << 4) + m16;
            uint2 u = *(const uint2*)(hTb + ((size_t)col << 8) + n0 + (rb << 4) + (quad << 2));
            hv[rb][cb][0] = bf2f((unsigned short)(u.x & 0xffff));
            hv[rb][cb][1] = bf2f((unsigned short)(u.x >> 16));
            hv[rb][cb][2] = bf2f((unsigned short)(u.y & 0xffff));
            hv[rb][cb][3] = bf2f((unsigned short)(u.y >> 16));
        }

    // ---- r and z ----
    f32x4 racc[2][2], zacc[2][2];
    #pragma unroll
    for (int rb = 0; rb < 2; ++rb)
        #pragma unroll
        for (int cb = 0; cb < 2; ++cb) {
            racc[rb][cb] = (f32x4){0.f, 0.f, 0.f, 0.f};
            zacc[rb][cb] = (f32x4){0.f, 0.f, 0.f, 0.f};
        }
    #pragma unroll 2
    for (int ks = 0; ks < 8; ++ks) {
        bf16x8 af[2], bfr[2], bfz[2];
        #pragma unroll
        for (int rb = 0; rb < 2; ++rb)
            af[rb] = *(const bf16x8*)(ahS + ((rb << 4) + m16) * 264 + (ks << 5) + (quad << 3));
        #pragma unroll
        for (int cb = 0; cb < 2; ++cb) {
            int dout = wcol + (cb << 4) + m16;
            bfr[cb] = *(const bf16x8*)(WrT + (dout << 8) + (ks << 5) + (quad << 3));
            bfz[cb] = *(const bf16x8*)(WzT + (dout << 8) + (ks << 5) + (quad << 3));
        }
        #pragma unroll
        for (int rb = 0; rb < 2; ++rb)
            #pragma unroll
            for (int cb = 0; cb < 2; ++cb) {
                racc[rb][cb] = __builtin_amdgcn_mfma_f32_16x16x32_bf16(af[rb], bfr[cb], racc[rb][cb], 0, 0, 0);
                zacc[rb][cb] = __builtin_amdgcn_mfma_f32_16x16x32_bf16(af[rb], bfz[cb], zacc[rb][cb], 0, 0, 0);
            }
    }
    float zv[2][2][4];
    {
        float brv[2], bzv[2];
        #pragma unroll
        for (int cb = 0; cb < 2; ++cb) {
            brv[cb] = br[wcol + (cb << 4) + m16];
            bzv[cb] = bz[wcol + (cb << 4) + m16];
        }
        #pragma unroll
        for (int rb = 0; rb < 2; ++rb)
            #pragma unroll
            for (int cb = 0; cb < 2; ++cb)
                #pragma unroll
                for (int r = 0; r < 4; ++r) {
                    racc[rb][cb][r] = sigmoidf_(racc[rb][cb][r] + brv[cb]);
                    zv[rb][cb][r]  = sigmoidf_(zacc[rb][cb][r] + bzv[cb]);
                }
    }
    __syncthreads();   // all ahS reads done -> safe to overwrite h-half

    #pragma unroll
    for (int rb = 0; rb < 2; ++rb)
        #pragma unroll
        for (int cb = 0; cb < 2; ++cb)
            #pragma unroll
            for (int r = 0; r < 4; ++r)
                ahS[((rb << 4) + (quad << 2) + r) * 264 + 128 + wcol + (cb << 4) + m16] =
                    f2bf(racc[rb][cb][r] * hv[rb][cb][r]);
    __syncthreads();

    // ---- h_tilde ----
    #pragma unroll
    for (int rb = 0; rb < 2; ++rb)
        #pragma unroll
        for (int cb = 0; cb < 2; ++cb) acc[rb][cb] = (f32x4){0.f, 0.f, 0.f, 0.f};
    #pragma unroll 2
    for (int ks = 0; ks < 8; ++ks) {
        bf16x8 af[2], bf[2];
        #pragma unroll
        for (int rb = 0; rb < 2; ++rb)
            af[rb] = *(const bf16x8*)(ahS + ((rb << 4) + m16) * 264 + (ks << 5) + (quad << 3));
        #pragma unroll
        for (int cb = 0; cb < 2; ++cb)
            bf[cb] = *(const bf16x8*)(WhT + ((wcol + (cb << 4) + m16) << 8) + (ks << 5) + (quad << 3));
        #pragma unroll
        for (int rb = 0; rb < 2; ++rb)
            #pragma unroll
            for (int cb = 0; cb < 2; ++cb)
                acc[rb][cb] = __builtin_amdgcn_mfma_f32_16x16x32_bf16(af[rb], bf[cb], acc[rb][cb], 0, 0, 0);
    }

    // ---- update + writes (hT only) ----
    {
        float bhv[2];
        #pragma unroll
        for (int cb = 0; cb < 2; ++cb) bhv[cb] = bh[wcol + (cb << 4) + m16];
        #pragma unroll
        for (int rb = 0; rb < 2; ++rb)
            #pragma unroll
            for (int cb = 0; cb < 2; ++cb) {
                int col = wcol + (cb << 4) + m16;
                unsigned short pk[4];
                #pragma unroll
                for (int r = 0; r < 4; ++r) {
                    float ht = tanhf_(acc[rb][cb][r] + bhv[cb]);
                    float hn = hv[rb][cb][r] + zv[rb][cb][r] * (ht - hv[rb][cb][r]);
                    pk[r] = f2bf(hn);
                }
                uint2 p;
                p.x = pack2(pk[0], pk[1]); p.y = pack2(pk[2], pk[3]);
                *(uint2*)(hT_o + ((size_t)(tb * 128 + col) << 8) + n0 + (rb << 4) + (quad << 2)) = p;
            }
    }
}

// ---------------------------------------------------------------------------
// fc: logits[b,c] = sum over col-major h (hT, t=15) + bfc. grid = 512.
// ---------------------------------------------------------------------------
__global__ __launch_bounds__(256) void k_fc(const unsigned short* __restrict__ hT,
                                            const float* __restrict__ Wfc,
                                            const float* __restrict__ bfc,
                                            float* __restrict__ out) {
    int bid = blockIdx.x;
    int b = bid >> 4, part = bid & 15;
    int tid = threadIdx.x;
    int tb = 15 * 32 + b;
    const unsigned short* hp = hT + ((size_t)tb << 15);
    int i = part * 2048 + tid * 8;       // linear col-major: i = d*256 + n
    int d = i >> 8, n = i & 255;
    uint4 hu = *(const uint4*)(hp + i);
    unsigned short hs[8];
    hs[0] = hu.x & 0xffff; hs[1] = hu.x >> 16;
    hs[2] = hu.y & 0xffff; hs[3] = hu.y >> 16;
    hs[4] = hu.z & 0xffff; hs[5] = hu.z >> 16;
    hs[6] = hu.w & 0xffff; hs[7] = hu.w >> 16;
    float a0 = 0.f, a1 = 0.f;
    #pragma unroll
    for (int k = 0; k < 8; ++k) {
        float v = bf2f(hs[k]);
        const float2 w = *(const float2*)(Wfc + ((size_t)(n + k) * 128 + d) * 2);
        a0 = fmaf(v, w.x, a0);
        a1 = fmaf(v, w.y, a1);
    }
    int wave = tid >> 6, lane = tid & 63;
    #pragma unroll
    for (int off = 32; off; off >>= 1) {
        a0 += __shfl_down(a0, off, 64);
        a1 += __shfl_down(a1, off, 64);
    }
    __shared__ float r0[4], r1[4];
    if (lane == 0) { r0[wave] = a0; r1[wave] = a1; }
    __syncthreads();
    if (tid == 0) {
        float s0 = r0[0] + r0[1] + r0[2] + r0[3];
        float s1 = r1[0] + r1[1] + r1[2] + r1[3];
        if (part == 0) { s0 += bfc[0]; s1 += bfc[1]; }
        atomicAdd(&out[b * 2 + 0], s0);
        atomicAdd(&out[b * 2 + 1], s1);
    }
}

// ---------------------------------------------------------------------------
extern "C" void kernel_launch(void* const* d_in, const int* in_sizes, int n_in,
                              void* d_out, int out_size, void* d_ws, size_t ws_size,
                              hipStream_t stream) {
    const float* x_all    = (const float*)d_in[0];
    const float* supports = (const float*)d_in[1];
    const float* Wgl = (const float*)d_in[2];
    const float* Wa  = (const float*)d_in[3];
    const float* ba  = (const float*)d_in[4];
    const float* Wr  = (const float*)d_in[5];
    const float* br  = (const float*)d_in[6];
    const float* Wz  = (const float*)d_in[7];
    const float* bz  = (const float*)d_in[8];
    const float* Wh  = (const float*)d_in[9];
    const float* bh  = (const float*)d_in[10];
    const float* Wfc = (const float*)d_in[11];
    const float* bfc = (const float*)d_in[12];
    float* out = (float*)d_out;

    char* p = (char*)d_ws;
    auto alloc = [&](size_t bytes) { char* r = p; p += (bytes + 255) & ~(size_t)255; return r; };

    unsigned short* AttA = (unsigned short*)alloc((size_t)TT * BB * NN * NN * 2);  // 64 MB
    unsigned short* hT0  = (unsigned short*)alloc((size_t)TT * BB * DD * NN * 2);  // 32 MB
    unsigned short* hT1  = (unsigned short*)alloc((size_t)TT * BB * DD * NN * 2);  // 32 MB
    unsigned short* WaT  = (unsigned short*)alloc(128 * 128 * 2);
    unsigned short* WrT  = (unsigned short*)alloc(256 * 128 * 2);
    unsigned short* WzT  = (unsigned short*)alloc(256 * 128 * 2);
    unsigned short* WhT  = (unsigned short*)alloc(256 * 128 * 2);
    // total ~128.2 MB

    // V (per t-group, GT*32*256*2048 bf16 = 64 MB) aliases hT0+hT1:
    // all gram work finishes before any hT buffer is written.
    unsigned short* V = hT0;

    k_wprep<<<128, 256, 0, stream>>>(Wa, Wr, Wz, Wh, WaT, WrT, WzT, WhT);

    for (int g = 0; g < TT / GT; ++g) {
        const float* xg = x_all + (size_t)g * GT * BB * NN * DD;
        k_buildV<<<GT * BB * NN, 128, 0, stream>>>(xg, Wgl, V);
        k_gram<<<8 * GT * BB, 256, 0, stream>>>(V, AttA + (size_t)g * GT * BB * NN * NN);
    }
    k_scan<<<2048, 256, 0, stream>>>(supports, AttA);
    k_hTinit<<<TT * BB * 32, 256, 0, stream>>>(x_all, hT0);

    const unsigned short* hT_in = hT0;
    for (int s = 0; s < NSTEPS; ++s) {
        unsigned short* hTo = (s & 1) ? hT0 : hT1;
        k_step<<<8 * 512, 256, 0, stream>>>(AttA, hT_in,
                                            WaT, ba, WrT, br, WzT, bz, WhT, bh,
                                            hTo);
        hT_in = hTo;
    }
    // after 5 steps (s=4) final h is in hT1
    hipMemsetAsync(d_out, 0, (size_t)out_size * sizeof(float), stream);
    k_fc<<<BB * 16, 256, 0, stream>>>(hT1, Wfc, bfc, out);
}

// Round 7
// 860.437 us; speedup vs baseline: 4.0972x; 1.9214x over previous
//
#include <hip/hip_runtime.h>
#include <math.h>

#define TT 16
#define BB 32
#define NN 256
#define DD 128
#define NSTEPS 5
#define SKIPF 0.3f
#define EPSF 1e-8f
#define GT 2            // t-group size for V materialization

// Workspace: AttA 64 + V 64 + Afin 4 + hT0 2 + hT1 2 + weights ~0.2 = ~136 MB
// (< ws budget; R4 showed ~192.4 MB overflows). No aliasing needed.
//
// KEY INSIGHT (R7): reference uses only outs[-1] -> GRU propagation for
// t=0..14 is dead code. Only the attention scan (gram for all t -> A_15)
// and the t=15 GRU chain are live.

typedef __attribute__((ext_vector_type(8))) short bf16x8;
typedef __attribute__((ext_vector_type(4))) float f32x4;

__device__ __forceinline__ unsigned short f2bf(float f) {
    union { float f; unsigned u; } v; v.f = f;
    unsigned r = (v.u + 0x7FFF + ((v.u >> 16) & 1)) >> 16;
    return (unsigned short)r;
}
__device__ __forceinline__ float bf2f(unsigned short u) {
    union { unsigned u; float f; } v; v.u = ((unsigned)u) << 16; return v.f;
}
__device__ __forceinline__ unsigned pack2(unsigned short a, unsigned short b) {
    return (unsigned)a | ((unsigned)b << 16);
}
__device__ __forceinline__ float sigmoidf_(float x) {
    return 1.0f / (1.0f + __expf(-x));
}
__device__ __forceinline__ float tanhf_(float x) {
    return 1.0f - 2.0f / (__expf(2.0f * x) + 1.0f);
}
// async global->LDS, 16B per lane; lds base must be wave-uniform
__device__ __forceinline__ void gload16(const void* g, void* l) {
    __builtin_amdgcn_global_load_lds(
        (const __attribute__((address_space(1))) unsigned int*)g,
        (__attribute__((address_space(3))) unsigned int*)l, 16, 0, 0);
}

// ---------------------------------------------------------------------------
// buildV (per t-group): V[tbl,n,h*128+d] = bf16( x*Wgl[h]/(||x*w_h||+eps) )
// grid = GT*32*256 blocks x 128 threads; x pre-offset to group start
// ---------------------------------------------------------------------------
__global__ __launch_bounds__(128) void k_buildV(const float* __restrict__ x,
                                                const float* __restrict__ Wgl,
                                                unsigned short* __restrict__ V) {
    int bid = blockIdx.x;
    int tbl = bid >> 8, n = bid & 255;
    int d = threadIdx.x;
    __shared__ float part[16][2];
    float xv = x[((size_t)(tbl * 256 + n) << 7) + d];
    float vv[16];
    int wave = d >> 6, lane = d & 63;
    #pragma unroll
    for (int h = 0; h < 16; ++h) {
        float v = xv * Wgl[(h << 7) + d];
        vv[h] = v;
        float s = v * v;
        #pragma unroll
        for (int off = 32; off; off >>= 1) s += __shfl_down(s, off, 64);
        if (lane == 0) part[h][wave] = s;
    }
    __syncthreads();
    unsigned short* Vr = V + ((size_t)(tbl * 256 + n) << 11);
    #pragma unroll
    for (int h = 0; h < 16; ++h) {
        float inv = 1.0f / (sqrtf(part[h][0] + part[h][1]) + EPSF);
        Vr[(h << 7) + d] = f2bf(vv[h] * inv);
    }
}

// ---------------------------------------------------------------------------
// gram (per t-group): attn = 0.7 * rownorm(relu(V V^T))  -> bf16
// grid = 8 rg x (GT*32) tbl = 512 blocks, 256 threads, 64.5 KB LDS.
// m97-style async global_load_lds staging with XOR-16 swizzle.
// ---------------------------------------------------------------------------
__global__ __launch_bounds__(256) void k_gram(const unsigned short* __restrict__ V,
                                              unsigned short* __restrict__ attn) {
    int bid = blockIdx.x;
    int tbl = bid & (GT * 32 - 1);
    int rg  = bid / (GT * 32);          // 0..7
    int n0 = rg << 5;
    int tid = threadIdx.x;
    int wave = tid >> 6, lane = tid & 63;
    int m16 = lane & 15, quad = lane >> 4;

    __shared__ unsigned short Vs[256 * 128];   // 64 KB chunk (256 rows x 128 k)
    __shared__ float rsum[4][32];

    f32x4 acc[2][4];
    #pragma unroll
    for (int rb = 0; rb < 2; ++rb)
        #pragma unroll
        for (int cb = 0; cb < 4; ++cb) acc[rb][cb] = (f32x4){0.f, 0.f, 0.f, 0.f};

    const unsigned short* Vb = V + ((size_t)tbl << 19);   // tbl*256*2048
    const char* Vsb = (const char*)Vs;

    int lrow_off = lane >> 4;          // 0..3 row within 4-row group
    int gslot = lane & 15;             // destination 16B slot

    for (int kc = 0; kc < 16; ++kc) {
        #pragma unroll
        for (int j = 0; j < 16; ++j) {
            int r0 = (wave << 6) + (j << 2);          // wave-uniform
            int grow = r0 + lrow_off;
            int gsw = gslot ^ (grow & 15);            // source group (swizzled)
            const unsigned short* src = Vb + ((size_t)grow << 11) + (kc << 7) + (gsw << 3);
            gload16(src, Vs + (r0 << 7));
        }
        __syncthreads();

        #pragma unroll
        for (int ks = 0; ks < 4; ++ks) {
            int sw = (((ks << 2) | quad) ^ m16) << 4;   // byte offset of 16B group
            bf16x8 afr[2], bfr[4];
            #pragma unroll
            for (int rb = 0; rb < 2; ++rb) {
                int rr = n0 + (rb << 4) + m16;
                afr[rb] = *(const bf16x8*)(Vsb + (rr << 8) + sw);
            }
            #pragma unroll
            for (int cb = 0; cb < 4; ++cb) {
                int cc = (wave << 6) + (cb << 4) + m16;
                bfr[cb] = *(const bf16x8*)(Vsb + (cc << 8) + sw);
            }
            #pragma unroll
            for (int rb = 0; rb < 2; ++rb)
                #pragma unroll
                for (int cb = 0; cb < 4; ++cb)
                    acc[rb][cb] = __builtin_amdgcn_mfma_f32_16x16x32_bf16(afr[rb], bfr[cb], acc[rb][cb], 0, 0, 0);
        }
        __syncthreads();
    }

    // relu + rowsum + normalize (x0.7) -> bf16 attn
    float rs[2][4];
    #pragma unroll
    for (int rb = 0; rb < 2; ++rb)
        #pragma unroll
        for (int r = 0; r < 4; ++r) {
            float s = 0.f;
            #pragma unroll
            for (int cb = 0; cb < 4; ++cb) {
                float v = fmaxf(acc[rb][cb][r], 0.0f);
                acc[rb][cb][r] = v;
                s += v;
            }
            rs[rb][r] = s;
        }
    #pragma unroll
    for (int m = 1; m < 16; m <<= 1)
        #pragma unroll
        for (int rb = 0; rb < 2; ++rb)
            #pragma unroll
            for (int r = 0; r < 4; ++r)
                rs[rb][r] += __shfl_xor(rs[rb][r], m, 64);
    if (m16 == 0) {
        #pragma unroll
        for (int rb = 0; rb < 2; ++rb)
            #pragma unroll
            for (int r = 0; r < 4; ++r)
                rsum[wave][(rb << 4) + (quad << 2) + r] = rs[rb][r];
    }
    __syncthreads();

    unsigned short* outb = attn + ((size_t)tbl << 16);
    #pragma unroll
    for (int rb = 0; rb < 2; ++rb) {
        #pragma unroll
        for (int r = 0; r < 4; ++r) {
            int row = (rb << 4) + (quad << 2) + r;
            float tot = rsum[0][row] + rsum[1][row] + rsum[2][row] + rsum[3][row];
            float inv = (1.0f - SKIPF) / (tot + 16.0f * EPSF);
            #pragma unroll
            for (int cb = 0; cb < 4; ++cb) {
                int col = (wave << 6) + (cb << 4) + m16;
                outb[((size_t)(n0 + row) << 8) + col] = f2bf(acc[rb][cb][r] * inv);
            }
        }
    }
}

// ---------------------------------------------------------------------------
// scanlast: A_15 = 0.3^16*supports-chain folded: a=supports; a=0.3a+attn_t.
// f32 accumulator carried in registers (same arithmetic as the old k_scan).
// Writes ONLY the final A_15 as bf16 -> Afin. grid = 2048 x 256.
// ---------------------------------------------------------------------------
__global__ __launch_bounds__(256) void k_scanlast(const float* __restrict__ supports,
                                                  const unsigned short* __restrict__ AttA,
                                                  unsigned short* __restrict__ Afin) {
    size_t flat = ((size_t)blockIdx.x * 256 + threadIdx.x) * 4;
    float4 s4 = *(const float4*)(supports + flat);
    float a0 = s4.x, a1 = s4.y, a2 = s4.z, a3 = s4.w;
    #pragma unroll
    for (int t = 0; t < TT; ++t) {
        const unsigned short* p = AttA + ((size_t)t << 21) + flat;
        uint2 u = *(const uint2*)p;
        a0 = SKIPF * a0 + bf2f((unsigned short)(u.x & 0xffff));
        a1 = SKIPF * a1 + bf2f((unsigned short)(u.x >> 16));
        a2 = SKIPF * a2 + bf2f((unsigned short)(u.y & 0xffff));
        a3 = SKIPF * a3 + bf2f((unsigned short)(u.y >> 16));
    }
    uint2 o;
    o.x = pack2(f2bf(a0), f2bf(a1));
    o.y = pack2(f2bf(a2), f2bf(a3));
    *(uint2*)(Afin + flat) = o;
}

// ---------------------------------------------------------------------------
// hTinit: hT0[b][d][n] = bf16(x15[b][n][d]) for b=0..31. grid 32*32 blocks.
// ---------------------------------------------------------------------------
__global__ __launch_bounds__(256) void k_hTinit(const float* __restrict__ x15,
                                                unsigned short* __restrict__ hT) {
    int bid = blockIdx.x;
    int b = bid >> 5; int r = bid & 31; int d0 = (r >> 3) << 5; int n0 = (r & 7) << 5;
    __shared__ float tl[32][33];
    int tid = threadIdx.x;
    int i = tid >> 5, j = tid & 31;
    #pragma unroll
    for (int s = 0; s < 4; ++s) {
        int nl = (s << 3) + i;
        tl[nl][j] = x15[((size_t)(b * 256 + n0 + nl) << 7) + d0 + j];
    }
    __syncthreads();
    #pragma unroll
    for (int s = 0; s < 4; ++s) {
        int dd = (s << 3) + i;
        hT[((size_t)(b * 128 + d0 + dd) << 8) + n0 + j] = f2bf(tl[j][dd]);
    }
}

// ---------------------------------------------------------------------------
// wprep: bf16-transposed weights WT[dout][k]
// ---------------------------------------------------------------------------
__global__ __launch_bounds__(256) void k_wprep(const float* __restrict__ Wa,
                                               const float* __restrict__ Wr,
                                               const float* __restrict__ Wz,
                                               const float* __restrict__ Wh,
                                               unsigned short* __restrict__ WaT,
                                               unsigned short* __restrict__ WrT,
                                               unsigned short* __restrict__ WzT,
                                               unsigned short* __restrict__ WhT) {
    int idx = blockIdx.x * 256 + threadIdx.x;     // 0..32767
    if (idx < 16384) {
        int dout = idx >> 7, din = idx & 127;
        WaT[idx] = f2bf(Wa[(din << 7) + dout]);
    }
    {
        int dout = idx >> 8, dk = idx & 255;
        WrT[idx] = f2bf(Wr[(dk << 7) + dout]);
        WzT[idx] = f2bf(Wz[(dk << 7) + dout]);
        WhT[idx] = f2bf(Wh[(dk << 7) + dout]);
    }
}

// ---------------------------------------------------------------------------
// step: fused GGNN/GRU step for t=15 only: b = 0..31, 32-row tiles.
// h state in hT (bf16, [b][d][n]). grid = 8 rg x 32 b = 256 blocks.
// ---------------------------------------------------------------------------
__global__ __launch_bounds__(256) void k_step(
    const unsigned short* __restrict__ Afin,
    const unsigned short* __restrict__ hT,
    const unsigned short* __restrict__ WaT, const float* __restrict__ ba,
    const unsigned short* __restrict__ WrT, const float* __restrict__ br,
    const unsigned short* __restrict__ WzT, const float* __restrict__ bz,
    const unsigned short* __restrict__ WhT, const float* __restrict__ bh,
    unsigned short* __restrict__ hT_o) {

    int bid = blockIdx.x;
    int b = bid & 31, rg = bid >> 5;
    int n0 = rg << 5;
    int tid = threadIdx.x;
    int wave = tid >> 6, lane = tid & 63;
    int m16 = lane & 15, quad = lane >> 4;
    int wcol = wave << 5;

    __shared__ unsigned short msgS[32 * 136];
    __shared__ unsigned short ahS[32 * 264];   // k 0..127 = a, 128..255 = h (later r*h)

    const unsigned short* hTb = hT + ((size_t)b << 15);

    // stage h-half of ahS from hT (transpose: ahS[row][128+d] = hT[d][n0+row])
    #pragma unroll
    for (int j = 0; j < 16; ++j) {
        int idx = (j << 8) + tid;            // 0..4095
        int d = idx >> 5, row = idx & 31;
        ahS[row * 264 + 128 + d] = hTb[((size_t)d << 8) + n0 + row];
    }

    // ---- bmm: msg = A_tile @ h  (K=256) ----
    f32x4 acc[2][2];
    #pragma unroll
    for (int rb = 0; rb < 2; ++rb)
        #pragma unroll
        for (int cb = 0; cb < 2; ++cb) acc[rb][cb] = (f32x4){0.f, 0.f, 0.f, 0.f};

    const unsigned short* Ab = Afin + ((size_t)b << 16) + ((size_t)n0 << 8);
    #pragma unroll 2
    for (int ks = 0; ks < 8; ++ks) {
        bf16x8 af[2], bf[2];
        #pragma unroll
        for (int rb = 0; rb < 2; ++rb)
            af[rb] = *(const bf16x8*)(Ab + (((rb << 4) + m16) << 8) + (ks << 5) + (quad << 3));
        #pragma unroll
        for (int cb = 0; cb < 2; ++cb)
            bf[cb] = *(const bf16x8*)(hTb + ((wcol + (cb << 4) + m16) << 8) + (ks << 5) + (quad << 3));
        #pragma unroll
        for (int rb = 0; rb < 2; ++rb)
            #pragma unroll
            for (int cb = 0; cb < 2; ++cb)
                acc[rb][cb] = __builtin_amdgcn_mfma_f32_16x16x32_bf16(af[rb], bf[cb], acc[rb][cb], 0, 0, 0);
    }
    #pragma unroll
    for (int rb = 0; rb < 2; ++rb)
        #pragma unroll
        for (int cb = 0; cb < 2; ++cb)
            #pragma unroll
            for (int r = 0; r < 4; ++r)
                msgS[((rb << 4) + (quad << 2) + r) * 136 + wcol + (cb << 4) + m16] = f2bf(acc[rb][cb][r]);
    __syncthreads();   // covers h-half staging too

    // ---- a = msg @ Wa + ba ----
    #pragma unroll
    for (int rb = 0; rb < 2; ++rb)
        #pragma unroll
        for (int cb = 0; cb < 2; ++cb) acc[rb][cb] = (f32x4){0.f, 0.f, 0.f, 0.f};
    #pragma unroll
    for (int ks = 0; ks < 4; ++ks) {
        bf16x8 af[2], bf[2];
        #pragma unroll
        for (int rb = 0; rb < 2; ++rb)
            af[rb] = *(const bf16x8*)(msgS + ((rb << 4) + m16) * 136 + (ks << 5) + (quad << 3));
        #pragma unroll
        for (int cb = 0; cb < 2; ++cb)
            bf[cb] = *(const bf16x8*)(WaT + ((wcol + (cb << 4) + m16) << 7) + (ks << 5) + (quad << 3));
        #pragma unroll
        for (int rb = 0; rb < 2; ++rb)
            #pragma unroll
            for (int cb = 0; cb < 2; ++cb)
                acc[rb][cb] = __builtin_amdgcn_mfma_f32_16x16x32_bf16(af[rb], bf[cb], acc[rb][cb], 0, 0, 0);
    }
    {
        float bav[2];
        #pragma unroll
        for (int cb = 0; cb < 2; ++cb) bav[cb] = ba[wcol + (cb << 4) + m16];
        #pragma unroll
        for (int rb = 0; rb < 2; ++rb)
            #pragma unroll
            for (int cb = 0; cb < 2; ++cb)
                #pragma unroll
                for (int r = 0; r < 4; ++r)
                    ahS[((rb << 4) + (quad << 2) + r) * 264 + wcol + (cb << 4) + m16] =
                        f2bf(acc[rb][cb][r] + bav[cb]);
    }
    __syncthreads();

    // h_old (for r*h and final update): uint2 = 4 consecutive n at fixed col
    float hv[2][2][4];
    #pragma unroll
    for (int rb = 0; rb < 2; ++rb)
        #pragma unroll
        for (int cb = 0; cb < 2; ++cb) {
            int col = wcol + (cb << 4) + m16;
            uint2 u = *(const uint2*)(hTb + ((size_t)col << 8) + n0 + (rb << 4) + (quad << 2));
            hv[rb][cb][0] = bf2f((unsigned short)(u.x & 0xffff));
            hv[rb][cb][1] = bf2f((unsigned short)(u.x >> 16));
            hv[rb][cb][2] = bf2f((unsigned short)(u.y & 0xffff));
            hv[rb][cb][3] = bf2f((unsigned short)(u.y >> 16));
        }

    // ---- r and z ----
    f32x4 racc[2][2], zacc[2][2];
    #pragma unroll
    for (int rb = 0; rb < 2; ++rb)
        #pragma unroll
        for (int cb = 0; cb < 2; ++cb) {
            racc[rb][cb] = (f32x4){0.f, 0.f, 0.f, 0.f};
            zacc[rb][cb] = (f32x4){0.f, 0.f, 0.f, 0.f};
        }
    #pragma unroll 2
    for (int ks = 0; ks < 8; ++ks) {
        bf16x8 af[2], bfr[2], bfz[2];
        #pragma unroll
        for (int rb = 0; rb < 2; ++rb)
            af[rb] = *(const bf16x8*)(ahS + ((rb << 4) + m16) * 264 + (ks << 5) + (quad << 3));
        #pragma unroll
        for (int cb = 0; cb < 2; ++cb) {
            int dout = wcol + (cb << 4) + m16;
            bfr[cb] = *(const bf16x8*)(WrT + (dout << 8) + (ks << 5) + (quad << 3));
            bfz[cb] = *(const bf16x8*)(WzT + (dout << 8) + (ks << 5) + (quad << 3));
        }
        #pragma unroll
        for (int rb = 0; rb < 2; ++rb)
            #pragma unroll
            for (int cb = 0; cb < 2; ++cb) {
                racc[rb][cb] = __builtin_amdgcn_mfma_f32_16x16x32_bf16(af[rb], bfr[cb], racc[rb][cb], 0, 0, 0);
                zacc[rb][cb] = __builtin_amdgcn_mfma_f32_16x16x32_bf16(af[rb], bfz[cb], zacc[rb][cb], 0, 0, 0);
            }
    }
    float zv[2][2][4];
    {
        float brv[2], bzv[2];
        #pragma unroll
        for (int cb = 0; cb < 2; ++cb) {
            brv[cb] = br[wcol + (cb << 4) + m16];
            bzv[cb] = bz[wcol + (cb << 4) + m16];
        }
        #pragma unroll
        for (int rb = 0; rb < 2; ++rb)
            #pragma unroll
            for (int cb = 0; cb < 2; ++cb)
                #pragma unroll
                for (int r = 0; r < 4; ++r) {
                    racc[rb][cb][r] = sigmoidf_(racc[rb][cb][r] + brv[cb]);
                    zv[rb][cb][r]  = sigmoidf_(zacc[rb][cb][r] + bzv[cb]);
                }
    }
    __syncthreads();   // all ahS reads done -> safe to overwrite h-half

    #pragma unroll
    for (int rb = 0; rb < 2; ++rb)
        #pragma unroll
        for (int cb = 0; cb < 2; ++cb)
            #pragma unroll
            for (int r = 0; r < 4; ++r)
                ahS[((rb << 4) + (quad << 2) + r) * 264 + 128 + wcol + (cb << 4) + m16] =
                    f2bf(racc[rb][cb][r] * hv[rb][cb][r]);
    __syncthreads();

    // ---- h_tilde ----
    #pragma unroll
    for (int rb = 0; rb < 2; ++rb)
        #pragma unroll
        for (int cb = 0; cb < 2; ++cb) acc[rb][cb] = (f32x4){0.f, 0.f, 0.f, 0.f};
    #pragma unroll 2
    for (int ks = 0; ks < 8; ++ks) {
        bf16x8 af[2], bf[2];
        #pragma unroll
        for (int rb = 0; rb < 2; ++rb)
            af[rb] = *(const bf16x8*)(ahS + ((rb << 4) + m16) * 264 + (ks << 5) + (quad << 3));
        #pragma unroll
        for (int cb = 0; cb < 2; ++cb)
            bf[cb] = *(const bf16x8*)(WhT + ((wcol + (cb << 4) + m16) << 8) + (ks << 5) + (quad << 3));
        #pragma unroll
        for (int rb = 0; rb < 2; ++rb)
            #pragma unroll
            for (int cb = 0; cb < 2; ++cb)
                acc[rb][cb] = __builtin_amdgcn_mfma_f32_16x16x32_bf16(af[rb], bf[cb], acc[rb][cb], 0, 0, 0);
    }

    // ---- update + writes (hT only) ----
    {
        float bhv[2];
        #pragma unroll
        for (int cb = 0; cb < 2; ++cb) bhv[cb] = bh[wcol + (cb << 4) + m16];
        #pragma unroll
        for (int rb = 0; rb < 2; ++rb)
            #pragma unroll
            for (int cb = 0; cb < 2; ++cb) {
                int col = wcol + (cb << 4) + m16;
                unsigned short pk[4];
                #pragma unroll
                for (int r = 0; r < 4; ++r) {
                    float ht = tanhf_(acc[rb][cb][r] + bhv[cb]);
                    float hn = hv[rb][cb][r] + zv[rb][cb][r] * (ht - hv[rb][cb][r]);
                    pk[r] = f2bf(hn);
                }
                uint2 p;
                p.x = pack2(pk[0], pk[1]); p.y = pack2(pk[2], pk[3]);
                *(uint2*)(hT_o + ((size_t)(b * 128 + col) << 8) + n0 + (rb << 4) + (quad << 2)) = p;
            }
    }
}

// ---------------------------------------------------------------------------
// fc: logits[b,c] = sum over col-major h (hT1, b slice) + bfc. grid = 512.
// ---------------------------------------------------------------------------
__global__ __launch_bounds__(256) void k_fc(const unsigned short* __restrict__ hT,
                                            const float* __restrict__ Wfc,
                                            const float* __restrict__ bfc,
                                            float* __restrict__ out) {
    int bid = blockIdx.x;
    int b = bid >> 4, part = bid & 15;
    int tid = threadIdx.x;
    const unsigned short* hp = hT + ((size_t)b << 15);
    int i = part * 2048 + tid * 8;       // linear col-major: i = d*256 + n
    int d = i >> 8, n = i & 255;
    uint4 hu = *(const uint4*)(hp + i);
    unsigned short hs[8];
    hs[0] = hu.x & 0xffff; hs[1] = hu.x >> 16;
    hs[2] = hu.y & 0xffff; hs[3] = hu.y >> 16;
    hs[4] = hu.z & 0xffff; hs[5] = hu.z >> 16;
    hs[6] = hu.w & 0xffff; hs[7] = hu.w >> 16;
    float a0 = 0.f, a1 = 0.f;
    #pragma unroll
    for (int k = 0; k < 8; ++k) {
        float v = bf2f(hs[k]);
        const float2 w = *(const float2*)(Wfc + ((size_t)(n + k) * 128 + d) * 2);
        a0 = fmaf(v, w.x, a0);
        a1 = fmaf(v, w.y, a1);
    }
    int wave = tid >> 6, lane = tid & 63;
    #pragma unroll
    for (int off = 32; off; off >>= 1) {
        a0 += __shfl_down(a0, off, 64);
        a1 += __shfl_down(a1, off, 64);
    }
    __shared__ float r0[4], r1[4];
    if (lane == 0) { r0[wave] = a0; r1[wave] = a1; }
    __syncthreads();
    if (tid == 0) {
        float s0 = r0[0] + r0[1] + r0[2] + r0[3];
        float s1 = r1[0] + r1[1] + r1[2] + r1[3];
        if (part == 0) { s0 += bfc[0]; s1 += bfc[1]; }
        atomicAdd(&out[b * 2 + 0], s0);
        atomicAdd(&out[b * 2 + 1], s1);
    }
}

// ---------------------------------------------------------------------------
extern "C" void kernel_launch(void* const* d_in, const int* in_sizes, int n_in,
                              void* d_out, int out_size, void* d_ws, size_t ws_size,
                              hipStream_t stream) {
    const float* x_all    = (const float*)d_in[0];
    const float* supports = (const float*)d_in[1];
    const float* Wgl = (const float*)d_in[2];
    const float* Wa  = (const float*)d_in[3];
    const float* ba  = (const float*)d_in[4];
    const float* Wr  = (const float*)d_in[5];
    const float* br  = (const float*)d_in[6];
    const float* Wz  = (const float*)d_in[7];
    const float* bz  = (const float*)d_in[8];
    const float* Wh  = (const float*)d_in[9];
    const float* bh  = (const float*)d_in[10];
    const float* Wfc = (const float*)d_in[11];
    const float* bfc = (const float*)d_in[12];
    float* out = (float*)d_out;

    char* p = (char*)d_ws;
    auto alloc = [&](size_t bytes) { char* r = p; p += (bytes + 255) & ~(size_t)255; return r; };

    unsigned short* AttA = (unsigned short*)alloc((size_t)TT * BB * NN * NN * 2);      // 64 MB
    unsigned short* V    = (unsigned short*)alloc((size_t)GT * BB * NN * 2048 * 2);    // 64 MB
    unsigned short* Afin = (unsigned short*)alloc((size_t)BB * NN * NN * 2);           // 4 MB
    unsigned short* hT0  = (unsigned short*)alloc((size_t)BB * DD * NN * 2);           // 2 MB
    unsigned short* hT1  = (unsigned short*)alloc((size_t)BB * DD * NN * 2);           // 2 MB
    unsigned short* WaT  = (unsigned short*)alloc(128 * 128 * 2);
    unsigned short* WrT  = (unsigned short*)alloc(256 * 128 * 2);
    unsigned short* WzT  = (unsigned short*)alloc(256 * 128 * 2);
    unsigned short* WhT  = (unsigned short*)alloc(256 * 128 * 2);
    // total ~136.2 MB

    k_wprep<<<128, 256, 0, stream>>>(Wa, Wr, Wz, Wh, WaT, WrT, WzT, WhT);

    // gram path: needed for ALL t (to form A_15)
    for (int g = 0; g < TT / GT; ++g) {
        const float* xg = x_all + (size_t)g * GT * BB * NN * DD;
        k_buildV<<<GT * BB * NN, 128, 0, stream>>>(xg, Wgl, V);
        k_gram<<<8 * GT * BB, 256, 0, stream>>>(V, AttA + (size_t)g * GT * BB * NN * NN);
    }
    k_scanlast<<<2048, 256, 0, stream>>>(supports, AttA, Afin);

    // GRU path: ONLY t=15 is live (reference uses outs[-1] only)
    const float* x15 = x_all + (size_t)15 * BB * NN * DD;
    k_hTinit<<<BB * 32, 256, 0, stream>>>(x15, hT0);

    const unsigned short* hT_in = hT0;
    for (int s = 0; s < NSTEPS; ++s) {
        unsigned short* hTo = (s & 1) ? hT0 : hT1;
        k_step<<<8 * BB, 256, 0, stream>>>(Afin, hT_in,
                                           WaT, ba, WrT, br, WzT, bz, WhT, bh,
                                           hTo);
        hT_in = hTo;
    }
    // after 5 steps (s=4) final h is in hT1
    hipMemsetAsync(d_out, 0, (size_t)out_size * sizeof(float), stream);
    k_fc<<<BB * 16, 256, 0, stream>>>(hT1, Wfc, bfc, out);
}

// Round 8
// 580.347 us; speedup vs baseline: 6.0746x; 1.4826x over previous
//
#include <hip/hip_runtime.h>
#include <math.h>

#define TT 16
#define BB 32
#define NN 256
#define DD 128
#define NSTEPS 5
#define SKIPF 0.3f
#define EPSF 1e-8f
#define GT 2            // t-group size for V materialization

// Workspace: AttA 64 + V 64 + invn 8 + Afin 4 + hT0 2 + hT1 2 + w ~0.2 = ~144 MB
// (< ws budget; R4 showed ~192.4 MB overflows).
//
// R7 insight: reference uses only outs[-1] -> GRU for t=0..14 is dead code.
// R8: buildV split into k_norms (one dispatch, reduction) + k_buildVe
// (pure elementwise, write-BW bound) — kills the 61%-VALU shuffle hot spot.

typedef __attribute__((ext_vector_type(8))) short bf16x8;
typedef __attribute__((ext_vector_type(4))) float f32x4;

__device__ __forceinline__ unsigned short f2bf(float f) {
    union { float f; unsigned u; } v; v.f = f;
    unsigned r = (v.u + 0x7FFF + ((v.u >> 16) & 1)) >> 16;
    return (unsigned short)r;
}
__device__ __forceinline__ float bf2f(unsigned short u) {
    union { unsigned u; float f; } v; v.u = ((unsigned)u) << 16; return v.f;
}
__device__ __forceinline__ unsigned pack2(unsigned short a, unsigned short b) {
    return (unsigned)a | ((unsigned)b << 16);
}
__device__ __forceinline__ float sigmoidf_(float x) {
    return 1.0f / (1.0f + __expf(-x));
}
__device__ __forceinline__ float tanhf_(float x) {
    return 1.0f - 2.0f / (__expf(2.0f * x) + 1.0f);
}
// async global->LDS, 16B per lane; lds base must be wave-uniform
__device__ __forceinline__ void gload16(const void* g, void* l) {
    __builtin_amdgcn_global_load_lds(
        (const __attribute__((address_space(1))) unsigned int*)g,
        (__attribute__((address_space(3))) unsigned int*)l, 16, 0, 0);
}

// ---------------------------------------------------------------------------
// norms: invn[tb][h][n] = 1/(sqrt(sum_d x^2 w^2)+eps) for ALL tb in one shot.
// grid = TT*BB*16 blocks (tb, n-group of 16), 256 threads = 16 n x 16 h.
// ---------------------------------------------------------------------------
__global__ __launch_bounds__(256) void k_norms(const float* __restrict__ x,
                                               const float* __restrict__ Wgl,
                                               float* __restrict__ invn) {
    int bid = blockIdx.x;
    int tb = bid >> 4, ng = bid & 15;
    int n0 = ng << 4;
    int tid = threadIdx.x;
    __shared__ float xs[16][132];    // pad 132: (4n+d)%32 -> 2-way = free
    __shared__ float ws[16][128];    // w^2, h-row broadcast reads

    {
        int r = tid >> 4, c = (tid & 15) << 3;
        const float* src = x + ((size_t)(tb * 256 + n0 + r) << 7) + c;
        float4 a = *(const float4*)src;
        float4 b = *(const float4*)(src + 4);
        *(float4*)&xs[r][c] = a;
        *(float4*)&xs[r][c + 4] = b;
        const float* wsrc = Wgl + (r << 7) + c;   // r doubles as h
        float4 wa = *(const float4*)wsrc;
        float4 wb = *(const float4*)(wsrc + 4);
        ws[r][c + 0] = wa.x * wa.x; ws[r][c + 1] = wa.y * wa.y;
        ws[r][c + 2] = wa.z * wa.z; ws[r][c + 3] = wa.w * wa.w;
        ws[r][c + 4] = wb.x * wb.x; ws[r][c + 5] = wb.y * wb.y;
        ws[r][c + 6] = wb.z * wb.z; ws[r][c + 7] = wb.w * wb.w;
    }
    __syncthreads();

    int n_l = tid & 15, h = tid >> 4;
    float s = 0.f;
    #pragma unroll
    for (int d = 0; d < 128; d += 4) {
        float4 xv = *(const float4*)&xs[n_l][d];
        float4 wv = *(const float4*)&ws[h][d];
        s = fmaf(xv.x * xv.x, wv.x, s);
        s = fmaf(xv.y * xv.y, wv.y, s);
        s = fmaf(xv.z * xv.z, wv.z, s);
        s = fmaf(xv.w * xv.w, wv.w, s);
    }
    invn[((size_t)(tb * 16 + h) << 8) + n0 + n_l] = 1.0f / (sqrtf(s) + EPSF);
}

// ---------------------------------------------------------------------------
// buildVe (per t-group): pure elementwise V = bf16(x * w * invn).
// grid = 16384 blocks x 256; thread = (tbl, n, h, 8-elem d-chunk).
// x/invn pre-offset to group start. Write-BW bound (64 MB/dispatch).
// ---------------------------------------------------------------------------
__global__ __launch_bounds__(256) void k_buildVe(const float* __restrict__ x,
                                                 const float* __restrict__ Wgl,
                                                 const float* __restrict__ invn,
                                                 unsigned short* __restrict__ V) {
    int T = blockIdx.x * 256 + threadIdx.x;
    int dc = T & 15;            // d-chunk of 8
    int h  = (T >> 4) & 15;
    int n  = (T >> 8) & 255;
    int tbl = T >> 16;          // 0..GT*32-1
    const float* xp = x + ((size_t)(tbl * 256 + n) << 7) + (dc << 3);
    const float* wp = Wgl + (h << 7) + (dc << 3);
    float inv = invn[((size_t)(tbl * 16 + h) << 8) + n];
    float4 xa = *(const float4*)xp, xb = *(const float4*)(xp + 4);
    float4 wa = *(const float4*)wp, wb = *(const float4*)(wp + 4);
    uint4 o;
    o.x = pack2(f2bf(xa.x * wa.x * inv), f2bf(xa.y * wa.y * inv));
    o.y = pack2(f2bf(xa.z * wa.z * inv), f2bf(xa.w * wa.w * inv));
    o.z = pack2(f2bf(xb.x * wb.x * inv), f2bf(xb.y * wb.y * inv));
    o.w = pack2(f2bf(xb.z * wb.z * inv), f2bf(xb.w * wb.w * inv));
    *(uint4*)(V + ((size_t)(tbl * 256 + n) << 11) + (h << 7) + (dc << 3)) = o;
}

// ---------------------------------------------------------------------------
// gram (per t-group): attn = 0.7 * rownorm(relu(V V^T))  -> bf16
// grid = 8 rg x (GT*32) tbl = 512 blocks, 256 threads, 64.5 KB LDS.
// m97-style async global_load_lds staging with XOR-16 swizzle.
// ---------------------------------------------------------------------------
__global__ __launch_bounds__(256) void k_gram(const unsigned short* __restrict__ V,
                                              unsigned short* __restrict__ attn) {
    int bid = blockIdx.x;
    int tbl = bid & (GT * 32 - 1);
    int rg  = bid / (GT * 32);          // 0..7
    int n0 = rg << 5;
    int tid = threadIdx.x;
    int wave = tid >> 6, lane = tid & 63;
    int m16 = lane & 15, quad = lane >> 4;

    __shared__ unsigned short Vs[256 * 128];   // 64 KB chunk (256 rows x 128 k)
    __shared__ float rsum[4][32];

    f32x4 acc[2][4];
    #pragma unroll
    for (int rb = 0; rb < 2; ++rb)
        #pragma unroll
        for (int cb = 0; cb < 4; ++cb) acc[rb][cb] = (f32x4){0.f, 0.f, 0.f, 0.f};

    const unsigned short* Vb = V + ((size_t)tbl << 19);   // tbl*256*2048
    const char* Vsb = (const char*)Vs;

    int lrow_off = lane >> 4;          // 0..3 row within 4-row group
    int gslot = lane & 15;             // destination 16B slot

    for (int kc = 0; kc < 16; ++kc) {
        #pragma unroll
        for (int j = 0; j < 16; ++j) {
            int r0 = (wave << 6) + (j << 2);          // wave-uniform
            int grow = r0 + lrow_off;
            int gsw = gslot ^ (grow & 15);            // source group (swizzled)
            const unsigned short* src = Vb + ((size_t)grow << 11) + (kc << 7) + (gsw << 3);
            gload16(src, Vs + (r0 << 7));
        }
        __syncthreads();

        #pragma unroll
        for (int ks = 0; ks < 4; ++ks) {
            int sw = (((ks << 2) | quad) ^ m16) << 4;   // byte offset of 16B group
            bf16x8 afr[2], bfr[4];
            #pragma unroll
            for (int rb = 0; rb < 2; ++rb) {
                int rr = n0 + (rb << 4) + m16;
                afr[rb] = *(const bf16x8*)(Vsb + (rr << 8) + sw);
            }
            #pragma unroll
            for (int cb = 0; cb < 4; ++cb) {
                int cc = (wave << 6) + (cb << 4) + m16;
                bfr[cb] = *(const bf16x8*)(Vsb + (cc << 8) + sw);
            }
            #pragma unroll
            for (int rb = 0; rb < 2; ++rb)
                #pragma unroll
                for (int cb = 0; cb < 4; ++cb)
                    acc[rb][cb] = __builtin_amdgcn_mfma_f32_16x16x32_bf16(afr[rb], bfr[cb], acc[rb][cb], 0, 0, 0);
        }
        __syncthreads();
    }

    // relu + rowsum + normalize (x0.7) -> bf16 attn
    float rs[2][4];
    #pragma unroll
    for (int rb = 0; rb < 2; ++rb)
        #pragma unroll
        for (int r = 0; r < 4; ++r) {
            float s = 0.f;
            #pragma unroll
            for (int cb = 0; cb < 4; ++cb) {
                float v = fmaxf(acc[rb][cb][r], 0.0f);
                acc[rb][cb][r] = v;
                s += v;
            }
            rs[rb][r] = s;
        }
    #pragma unroll
    for (int m = 1; m < 16; m <<= 1)
        #pragma unroll
        for (int rb = 0; rb < 2; ++rb)
            #pragma unroll
            for (int r = 0; r < 4; ++r)
                rs[rb][r] += __shfl_xor(rs[rb][r], m, 64);
    if (m16 == 0) {
        #pragma unroll
        for (int rb = 0; rb < 2; ++rb)
            #pragma unroll
            for (int r = 0; r < 4; ++r)
                rsum[wave][(rb << 4) + (quad << 2) + r] = rs[rb][r];
    }
    __syncthreads();

    unsigned short* outb = attn + ((size_t)tbl << 16);
    #pragma unroll
    for (int rb = 0; rb < 2; ++rb) {
        #pragma unroll
        for (int r = 0; r < 4; ++r) {
            int row = (rb << 4) + (quad << 2) + r;
            float tot = rsum[0][row] + rsum[1][row] + rsum[2][row] + rsum[3][row];
            float inv = (1.0f - SKIPF) / (tot + 16.0f * EPSF);
            #pragma unroll
            for (int cb = 0; cb < 4; ++cb) {
                int col = (wave << 6) + (cb << 4) + m16;
                outb[((size_t)(n0 + row) << 8) + col] = f2bf(acc[rb][cb][r] * inv);
            }
        }
    }
}

// ---------------------------------------------------------------------------
// scanlast: a=supports; a=0.3a+attn_t; write only A_15 (bf16). grid 2048x256.
// ---------------------------------------------------------------------------
__global__ __launch_bounds__(256) void k_scanlast(const float* __restrict__ supports,
                                                  const unsigned short* __restrict__ AttA,
                                                  unsigned short* __restrict__ Afin) {
    size_t flat = ((size_t)blockIdx.x * 256 + threadIdx.x) * 4;
    float4 s4 = *(const float4*)(supports + flat);
    float a0 = s4.x, a1 = s4.y, a2 = s4.z, a3 = s4.w;
    #pragma unroll
    for (int t = 0; t < TT; ++t) {
        const unsigned short* p = AttA + ((size_t)t << 21) + flat;
        uint2 u = *(const uint2*)p;
        a0 = SKIPF * a0 + bf2f((unsigned short)(u.x & 0xffff));
        a1 = SKIPF * a1 + bf2f((unsigned short)(u.x >> 16));
        a2 = SKIPF * a2 + bf2f((unsigned short)(u.y & 0xffff));
        a3 = SKIPF * a3 + bf2f((unsigned short)(u.y >> 16));
    }
    uint2 o;
    o.x = pack2(f2bf(a0), f2bf(a1));
    o.y = pack2(f2bf(a2), f2bf(a3));
    *(uint2*)(Afin + flat) = o;
}

// ---------------------------------------------------------------------------
// hTinit: hT0[b][d][n] = bf16(x15[b][n][d]) for b=0..31. grid 32*32 blocks.
// ---------------------------------------------------------------------------
__global__ __launch_bounds__(256) void k_hTinit(const float* __restrict__ x15,
                                                unsigned short* __restrict__ hT) {
    int bid = blockIdx.x;
    int b = bid >> 5; int r = bid & 31; int d0 = (r >> 3) << 5; int n0 = (r & 7) << 5;
    __shared__ float tl[32][33];
    int tid = threadIdx.x;
    int i = tid >> 5, j = tid & 31;
    #pragma unroll
    for (int s = 0; s < 4; ++s) {
        int nl = (s << 3) + i;
        tl[nl][j] = x15[((size_t)(b * 256 + n0 + nl) << 7) + d0 + j];
    }
    __syncthreads();
    #pragma unroll
    for (int s = 0; s < 4; ++s) {
        int dd = (s << 3) + i;
        hT[((size_t)(b * 128 + d0 + dd) << 8) + n0 + j] = f2bf(tl[j][dd]);
    }
}

// ---------------------------------------------------------------------------
// wprep: bf16-transposed weights WT[dout][k]
// ---------------------------------------------------------------------------
__global__ __launch_bounds__(256) void k_wprep(const float* __restrict__ Wa,
                                               const float* __restrict__ Wr,
                                               const float* __restrict__ Wz,
                                               const float* __restrict__ Wh,
                                               unsigned short* __restrict__ WaT,
                                               unsigned short* __restrict__ WrT,
                                               unsigned short* __restrict__ WzT,
                                               unsigned short* __restrict__ WhT) {
    int idx = blockIdx.x * 256 + threadIdx.x;     // 0..32767
    if (idx < 16384) {
        int dout = idx >> 7, din = idx & 127;
        WaT[idx] = f2bf(Wa[(din << 7) + dout]);
    }
    {
        int dout = idx >> 8, dk = idx & 255;
        WrT[idx] = f2bf(Wr[(dk << 7) + dout]);
        WzT[idx] = f2bf(Wz[(dk << 7) + dout]);
        WhT[idx] = f2bf(Wh[(dk << 7) + dout]);
    }
}

// ---------------------------------------------------------------------------
// step: fused GGNN/GRU step for t=15 only: b = 0..31, 32-row tiles.
// h state in hT (bf16, [b][d][n]). grid = 8 rg x 32 b = 256 blocks.
// ---------------------------------------------------------------------------
__global__ __launch_bounds__(256) void k_step(
    const unsigned short* __restrict__ Afin,
    const unsigned short* __restrict__ hT,
    const unsigned short* __restrict__ WaT, const float* __restrict__ ba,
    const unsigned short* __restrict__ WrT, const float* __restrict__ br,
    const unsigned short* __restrict__ WzT, const float* __restrict__ bz,
    const unsigned short* __restrict__ WhT, const float* __restrict__ bh,
    unsigned short* __restrict__ hT_o) {

    int bid = blockIdx.x;
    int b = bid & 31, rg = bid >> 5;
    int n0 = rg << 5;
    int tid = threadIdx.x;
    int wave = tid >> 6, lane = tid & 63;
    int m16 = lane & 15, quad = lane >> 4;
    int wcol = wave << 5;

    __shared__ unsigned short msgS[32 * 136];
    __shared__ unsigned short ahS[32 * 264];   // k 0..127 = a, 128..255 = h (later r*h)

    const unsigned short* hTb = hT + ((size_t)b << 15);

    // stage h-half of ahS from hT (transpose: ahS[row][128+d] = hT[d][n0+row])
    #pragma unroll
    for (int j = 0; j < 16; ++j) {
        int idx = (j << 8) + tid;            // 0..4095
        int d = idx >> 5, row = idx & 31;
        ahS[row * 264 + 128 + d] = hTb[((size_t)d << 8) + n0 + row];
    }

    // ---- bmm: msg = A_tile @ h  (K=256) ----
    f32x4 acc[2][2];
    #pragma unroll
    for (int rb = 0; rb < 2; ++rb)
        #pragma unroll
        for (int cb = 0; cb < 2; ++cb) acc[rb][cb] = (f32x4){0.f, 0.f, 0.f, 0.f};

    const unsigned short* Ab = Afin + ((size_t)b << 16) + ((size_t)n0 << 8);
    #pragma unroll 2
    for (int ks = 0; ks < 8; ++ks) {
        bf16x8 af[2], bf[2];
        #pragma unroll
        for (int rb = 0; rb < 2; ++rb)
            af[rb] = *(const bf16x8*)(Ab + (((rb << 4) + m16) << 8) + (ks << 5) + (quad << 3));
        #pragma unroll
        for (int cb = 0; cb < 2; ++cb)
            bf[cb] = *(const bf16x8*)(hTb + ((wcol + (cb << 4) + m16) << 8) + (ks << 5) + (quad << 3));
        #pragma unroll
        for (int rb = 0; rb < 2; ++rb)
            #pragma unroll
            for (int cb = 0; cb < 2; ++cb)
                acc[rb][cb] = __builtin_amdgcn_mfma_f32_16x16x32_bf16(af[rb], bf[cb], acc[rb][cb], 0, 0, 0);
    }
    #pragma unroll
    for (int rb = 0; rb < 2; ++rb)
        #pragma unroll
        for (int cb = 0; cb < 2; ++cb)
            #pragma unroll
            for (int r = 0; r < 4; ++r)
                msgS[((rb << 4) + (quad << 2) + r) * 136 + wcol + (cb << 4) + m16] = f2bf(acc[rb][cb][r]);
    __syncthreads();   // covers h-half staging too

    // ---- a = msg @ Wa + ba ----
    #pragma unroll
    for (int rb = 0; rb < 2; ++rb)
        #pragma unroll
        for (int cb = 0; cb < 2; ++cb) acc[rb][cb] = (f32x4){0.f, 0.f, 0.f, 0.f};
    #pragma unroll
    for (int ks = 0; ks < 4; ++ks) {
        bf16x8 af[2], bf[2];
        #pragma unroll
        for (int rb = 0; rb < 2; ++rb)
            af[rb] = *(const bf16x8*)(msgS + ((rb << 4) + m16) * 136 + (ks << 5) + (quad << 3));
        #pragma unroll
        for (int cb = 0; cb < 2; ++cb)
            bf[cb] = *(const bf16x8*)(WaT + ((wcol + (cb << 4) + m16) << 7) + (ks << 5) + (quad << 3));
        #pragma unroll
        for (int rb = 0; rb < 2; ++rb)
            #pragma unroll
            for (int cb = 0; cb < 2; ++cb)
                acc[rb][cb] = __builtin_amdgcn_mfma_f32_16x16x32_bf16(af[rb], bf[cb], acc[rb][cb], 0, 0, 0);
    }
    {
        float bav[2];
        #pragma unroll
        for (int cb = 0; cb < 2; ++cb) bav[cb] = ba[wcol + (cb << 4) + m16];
        #pragma unroll
        for (int rb = 0; rb < 2; ++rb)
            #pragma unroll
            for (int cb = 0; cb < 2; ++cb)
                #pragma unroll
                for (int r = 0; r < 4; ++r)
                    ahS[((rb << 4) + (quad << 2) + r) * 264 + wcol + (cb << 4) + m16] =
                        f2bf(acc[rb][cb][r] + bav[cb]);
    }
    __syncthreads();

    // h_old (for r*h and final update): uint2 = 4 consecutive n at fixed col
    float hv[2][2][4];
    #pragma unroll
    for (int rb = 0; rb < 2; ++rb)
        #pragma unroll
        for (int cb = 0; cb < 2; ++cb) {
            int col = wcol + (cb << 4) + m16;
            uint2 u = *(const uint2*)(hTb + ((size_t)col << 8) + n0 + (rb << 4) + (quad << 2));
            hv[rb][cb][0] = bf2f((unsigned short)(u.x & 0xffff));
            hv[rb][cb][1] = bf2f((unsigned short)(u.x >> 16));
            hv[rb][cb][2] = bf2f((unsigned short)(u.y & 0xffff));
            hv[rb][cb][3] = bf2f((unsigned short)(u.y >> 16));
        }

    // ---- r and z ----
    f32x4 racc[2][2], zacc[2][2];
    #pragma unroll
    for (int rb = 0; rb < 2; ++rb)
        #pragma unroll
        for (int cb = 0; cb < 2; ++cb) {
            racc[rb][cb] = (f32x4){0.f, 0.f, 0.f, 0.f};
            zacc[rb][cb] = (f32x4){0.f, 0.f, 0.f, 0.f};
        }
    #pragma unroll 2
    for (int ks = 0; ks < 8; ++ks) {
        bf16x8 af[2], bfr[2], bfz[2];
        #pragma unroll
        for (int rb = 0; rb < 2; ++rb)
            af[rb] = *(const bf16x8*)(ahS + ((rb << 4) + m16) * 264 + (ks << 5) + (quad << 3));
        #pragma unroll
        for (int cb = 0; cb < 2; ++cb) {
            int dout = wcol + (cb << 4) + m16;
            bfr[cb] = *(const bf16x8*)(WrT + (dout << 8) + (ks << 5) + (quad << 3));
            bfz[cb] = *(const bf16x8*)(WzT + (dout << 8) + (ks << 5) + (quad << 3));
        }
        #pragma unroll
        for (int rb = 0; rb < 2; ++rb)
            #pragma unroll
            for (int cb = 0; cb < 2; ++cb) {
                racc[rb][cb] = __builtin_amdgcn_mfma_f32_16x16x32_bf16(af[rb], bfr[cb], racc[rb][cb], 0, 0, 0);
                zacc[rb][cb] = __builtin_amdgcn_mfma_f32_16x16x32_bf16(af[rb], bfz[cb], zacc[rb][cb], 0, 0, 0);
            }
    }
    float zv[2][2][4];
    {
        float brv[2], bzv[2];
        #pragma unroll
        for (int cb = 0; cb < 2; ++cb) {
            brv[cb] = br[wcol + (cb << 4) + m16];
            bzv[cb] = bz[wcol + (cb << 4) + m16];
        }
        #pragma unroll
        for (int rb = 0; rb < 2; ++rb)
            #pragma unroll
            for (int cb = 0; cb < 2; ++cb)
                #pragma unroll
                for (int r = 0; r < 4; ++r) {
                    racc[rb][cb][r] = sigmoidf_(racc[rb][cb][r] + brv[cb]);
                    zv[rb][cb][r]  = sigmoidf_(zacc[rb][cb][r] + bzv[cb]);
                }
    }
    __syncthreads();   // all ahS reads done -> safe to overwrite h-half

    #pragma unroll
    for (int rb = 0; rb < 2; ++rb)
        #pragma unroll
        for (int cb = 0; cb < 2; ++cb)
            #pragma unroll
            for (int r = 0; r < 4; ++r)
                ahS[((rb << 4) + (quad << 2) + r) * 264 + 128 + wcol + (cb << 4) + m16] =
                    f2bf(racc[rb][cb][r] * hv[rb][cb][r]);
    __syncthreads();

    // ---- h_tilde ----
    #pragma unroll
    for (int rb = 0; rb < 2; ++rb)
        #pragma unroll
        for (int cb = 0; cb < 2; ++cb) acc[rb][cb] = (f32x4){0.f, 0.f, 0.f, 0.f};
    #pragma unroll 2
    for (int ks = 0; ks < 8; ++ks) {
        bf16x8 af[2], bf[2];
        #pragma unroll
        for (int rb = 0; rb < 2; ++rb)
            af[rb] = *(const bf16x8*)(ahS + ((rb << 4) + m16) * 264 + (ks << 5) + (quad << 3));
        #pragma unroll
        for (int cb = 0; cb < 2; ++cb)
            bf[cb] = *(const bf16x8*)(WhT + ((wcol + (cb << 4) + m16) << 8) + (ks << 5) + (quad << 3));
        #pragma unroll
        for (int rb = 0; rb < 2; ++rb)
            #pragma unroll
            for (int cb = 0; cb < 2; ++cb)
                acc[rb][cb] = __builtin_amdgcn_mfma_f32_16x16x32_bf16(af[rb], bf[cb], acc[rb][cb], 0, 0, 0);
    }

    // ---- update + writes (hT only) ----
    {
        float bhv[2];
        #pragma unroll
        for (int cb = 0; cb < 2; ++cb) bhv[cb] = bh[wcol + (cb << 4) + m16];
        #pragma unroll
        for (int rb = 0; rb < 2; ++rb)
            #pragma unroll
            for (int cb = 0; cb < 2; ++cb) {
                int col = wcol + (cb << 4) + m16;
                unsigned short pk[4];
                #pragma unroll
                for (int r = 0; r < 4; ++r) {
                    float ht = tanhf_(acc[rb][cb][r] + bhv[cb]);
                    float hn = hv[rb][cb][r] + zv[rb][cb][r] * (ht - hv[rb][cb][r]);
                    pk[r] = f2bf(hn);
                }
                uint2 p;
                p.x = pack2(pk[0], pk[1]); p.y = pack2(pk[2], pk[3]);
                *(uint2*)(hT_o + ((size_t)(b * 128 + col) << 8) + n0 + (rb << 4) + (quad << 2)) = p;
            }
    }
}

// ---------------------------------------------------------------------------
// fc: logits[b,c] = sum over col-major h (hT1, b slice) + bfc. grid = 512.
// ---------------------------------------------------------------------------
__global__ __launch_bounds__(256) void k_fc(const unsigned short* __restrict__ hT,
                                            const float* __restrict__ Wfc,
                                            const float* __restrict__ bfc,
                                            float* __restrict__ out) {
    int bid = blockIdx.x;
    int b = bid >> 4, part = bid & 15;
    int tid = threadIdx.x;
    const unsigned short* hp = hT + ((size_t)b << 15);
    int i = part * 2048 + tid * 8;       // linear col-major: i = d*256 + n
    int d = i >> 8, n = i & 255;
    uint4 hu = *(const uint4*)(hp + i);
    unsigned short hs[8];
    hs[0] = hu.x & 0xffff; hs[1] = hu.x >> 16;
    hs[2] = hu.y & 0xffff; hs[3] = hu.y >> 16;
    hs[4] = hu.z & 0xffff; hs[5] = hu.z >> 16;
    hs[6] = hu.w & 0xffff; hs[7] = hu.w >> 16;
    float a0 = 0.f, a1 = 0.f;
    #pragma unroll
    for (int k = 0; k < 8; ++k) {
        float v = bf2f(hs[k]);
        const float2 w = *(const float2*)(Wfc + ((size_t)(n + k) * 128 + d) * 2);
        a0 = fmaf(v, w.x, a0);
        a1 = fmaf(v, w.y, a1);
    }
    int wave = tid >> 6, lane = tid & 63;
    #pragma unroll
    for (int off = 32; off; off >>= 1) {
        a0 += __shfl_down(a0, off, 64);
        a1 += __shfl_down(a1, off, 64);
    }
    __shared__ float r0[4], r1[4];
    if (lane == 0) { r0[wave] = a0; r1[wave] = a1; }
    __syncthreads();
    if (tid == 0) {
        float s0 = r0[0] + r0[1] + r0[2] + r0[3];
        float s1 = r1[0] + r1[1] + r1[2] + r1[3];
        if (part == 0) { s0 += bfc[0]; s1 += bfc[1]; }
        atomicAdd(&out[b * 2 + 0], s0);
        atomicAdd(&out[b * 2 + 1], s1);
    }
}

// ---------------------------------------------------------------------------
extern "C" void kernel_launch(void* const* d_in, const int* in_sizes, int n_in,
                              void* d_out, int out_size, void* d_ws, size_t ws_size,
                              hipStream_t stream) {
    const float* x_all    = (const float*)d_in[0];
    const float* supports = (const float*)d_in[1];
    const float* Wgl = (const float*)d_in[2];
    const float* Wa  = (const float*)d_in[3];
    const float* ba  = (const float*)d_in[4];
    const float* Wr  = (const float*)d_in[5];
    const float* br  = (const float*)d_in[6];
    const float* Wz  = (const float*)d_in[7];
    const float* bz  = (const float*)d_in[8];
    const float* Wh  = (const float*)d_in[9];
    const float* bh  = (const float*)d_in[10];
    const float* Wfc = (const float*)d_in[11];
    const float* bfc = (const float*)d_in[12];
    float* out = (float*)d_out;

    char* p = (char*)d_ws;
    auto alloc = [&](size_t bytes) { char* r = p; p += (bytes + 255) & ~(size_t)255; return r; };

    unsigned short* AttA = (unsigned short*)alloc((size_t)TT * BB * NN * NN * 2);      // 64 MB
    unsigned short* V    = (unsigned short*)alloc((size_t)GT * BB * NN * 2048 * 2);    // 64 MB
    float* invn          = (float*)alloc((size_t)TT * BB * 16 * NN * 4);               // 8 MB
    unsigned short* Afin = (unsigned short*)alloc((size_t)BB * NN * NN * 2);           // 4 MB
    unsigned short* hT0  = (unsigned short*)alloc((size_t)BB * DD * NN * 2);           // 2 MB
    unsigned short* hT1  = (unsigned short*)alloc((size_t)BB * DD * NN * 2);           // 2 MB
    unsigned short* WaT  = (unsigned short*)alloc(128 * 128 * 2);
    unsigned short* WrT  = (unsigned short*)alloc(256 * 128 * 2);
    unsigned short* WzT  = (unsigned short*)alloc(256 * 128 * 2);
    unsigned short* WhT  = (unsigned short*)alloc(256 * 128 * 2);
    // total ~144.2 MB

    k_wprep<<<128, 256, 0, stream>>>(Wa, Wr, Wz, Wh, WaT, WrT, WzT, WhT);
    k_norms<<<TT * BB * 16, 256, 0, stream>>>(x_all, Wgl, invn);

    // gram path: needed for ALL t (to form A_15)
    for (int g = 0; g < TT / GT; ++g) {
        const float* xg = x_all + (size_t)g * GT * BB * NN * DD;
        const float* invg = invn + (size_t)g * GT * BB * 16 * NN;
        k_buildVe<<<16384, 256, 0, stream>>>(xg, Wgl, invg, V);
        k_gram<<<8 * GT * BB, 256, 0, stream>>>(V, AttA + (size_t)g * GT * BB * NN * NN);
    }
    k_scanlast<<<2048, 256, 0, stream>>>(supports, AttA, Afin);

    // GRU path: ONLY t=15 is live (reference uses outs[-1] only)
    const float* x15 = x_all + (size_t)15 * BB * NN * DD;
    k_hTinit<<<BB * 32, 256, 0, stream>>>(x15, hT0);

    const unsigned short* hT_in = hT0;
    for (int s = 0; s < NSTEPS; ++s) {
        unsigned short* hTo = (s & 1) ? hT0 : hT1;
        k_step<<<8 * BB, 256, 0, stream>>>(Afin, hT_in,
                                           WaT, ba, WrT, br, WzT, bz, WhT, bh,
                                           hTo);
        hT_in = hTo;
    }
    // after 5 steps (s=4) final h is in hT1
    hipMemsetAsync(d_out, 0, (size_t)out_size * sizeof(float), stream);
    k_fc<<<BB * 16, 256, 0, stream>>>(hT1, Wfc, bfc, out);
}

// Round 9
// 463.306 us; speedup vs baseline: 7.6092x; 1.2526x over previous
//
#include <hip/hip_runtime.h>
#include <math.h>

#define TT 16
#define BB 32
#define NN 256
#define DD 128
#define NSTEPS 5
#define SKIPF 0.3f
#define EPSF 1e-8f

// Workspace (ws_size = 256 MiB per harness fill): AttA 64 + xb 32 + invn 8 +
// Afin 4 + hT0 2 + hT1 2 + weights ~0.2 = ~112.5 MB.
//
// R7: only outs[-1] is live -> GRU for t<15 is dead code.
// R9: V eliminated. gram2 stages bf16(x) once (64 KB/block) and computes the
// 16 per-head K=128 gram GEMMs with w^2-scaled A-fragments, invn applied in
// the per-h epilogue. 16x less DMA, no 64 MB V writes, one dispatch for all t.

typedef __attribute__((ext_vector_type(8))) short bf16x8;
typedef __attribute__((ext_vector_type(4))) float f32x4;

__device__ __forceinline__ unsigned short f2bf(float f) {
    union { float f; unsigned u; } v; v.f = f;
    unsigned r = (v.u + 0x7FFF + ((v.u >> 16) & 1)) >> 16;
    return (unsigned short)r;
}
__device__ __forceinline__ float bf2f(unsigned short u) {
    union { unsigned u; float f; } v; v.u = ((unsigned)u) << 16; return v.f;
}
__device__ __forceinline__ unsigned pack2(unsigned short a, unsigned short b) {
    return (unsigned)a | ((unsigned)b << 16);
}
__device__ __forceinline__ float lo2f(unsigned u) {
    union { unsigned u; float f; } v; v.u = u << 16; return v.f;
}
__device__ __forceinline__ float hi2f(unsigned u) {
    union { unsigned u; float f; } v; v.u = u & 0xffff0000u; return v.f;
}
__device__ __forceinline__ unsigned pkbf(float a, float b) {   // round-half-up pack
    union { float f; unsigned u; } x, y; x.f = a; y.f = b;
    return ((x.u + 0x8000u) >> 16) | ((y.u + 0x8000u) & 0xffff0000u);
}
__device__ __forceinline__ float sigmoidf_(float x) {
    return 1.0f / (1.0f + __expf(-x));
}
__device__ __forceinline__ float tanhf_(float x) {
    return 1.0f - 2.0f / (__expf(2.0f * x) + 1.0f);
}
// async global->LDS, 16B per lane; lds base must be wave-uniform
__device__ __forceinline__ void gload16(const void* g, void* l) {
    __builtin_amdgcn_global_load_lds(
        (const __attribute__((address_space(1))) unsigned int*)g,
        (__attribute__((address_space(3))) unsigned int*)l, 16, 0, 0);
}

// ---------------------------------------------------------------------------
// xbf: xb = bf16(x) for ALL 16.7M elements. grid 16384 x 256, 4 elems/thread.
// ---------------------------------------------------------------------------
__global__ __launch_bounds__(256) void k_xbf(const float* __restrict__ x,
                                             unsigned short* __restrict__ xb) {
    size_t idx = ((size_t)blockIdx.x * 256 + threadIdx.x) * 4;
    float4 v = *(const float4*)(x + idx);
    uint2 o;
    o.x = pack2(f2bf(v.x), f2bf(v.y));
    o.y = pack2(f2bf(v.z), f2bf(v.w));
    *(uint2*)(xb + idx) = o;
}

// ---------------------------------------------------------------------------
// norms: invn[tb][h][n] = 1/(sqrt(sum_d x^2 w^2)+eps) for ALL tb in one shot.
// grid = TT*BB*16 blocks (tb, n-group of 16), 256 threads = 16 n x 16 h.
// ---------------------------------------------------------------------------
__global__ __launch_bounds__(256) void k_norms(const float* __restrict__ x,
                                               const float* __restrict__ Wgl,
                                               float* __restrict__ invn) {
    int bid = blockIdx.x;
    int tb = bid >> 4, ng = bid & 15;
    int n0 = ng << 4;
    int tid = threadIdx.x;
    __shared__ float xs[16][132];    // pad 132: 2-way aliasing = free
    __shared__ float ws[16][128];    // w^2, h-row broadcast reads

    {
        int r = tid >> 4, c = (tid & 15) << 3;
        const float* src = x + ((size_t)(tb * 256 + n0 + r) << 7) + c;
        float4 a = *(const float4*)src;
        float4 b = *(const float4*)(src + 4);
        *(float4*)&xs[r][c] = a;
        *(float4*)&xs[r][c + 4] = b;
        const float* wsrc = Wgl + (r << 7) + c;   // r doubles as h
        float4 wa = *(const float4*)wsrc;
        float4 wb = *(const float4*)(wsrc + 4);
        ws[r][c + 0] = wa.x * wa.x; ws[r][c + 1] = wa.y * wa.y;
        ws[r][c + 2] = wa.z * wa.z; ws[r][c + 3] = wa.w * wa.w;
        ws[r][c + 4] = wb.x * wb.x; ws[r][c + 5] = wb.y * wb.y;
        ws[r][c + 6] = wb.z * wb.z; ws[r][c + 7] = wb.w * wb.w;
    }
    __syncthreads();

    int n_l = tid & 15, h = tid >> 4;
    float s = 0.f;
    #pragma unroll
    for (int d = 0; d < 128; d += 4) {
        float4 xv = *(const float4*)&xs[n_l][d];
        float4 wv = *(const float4*)&ws[h][d];
        s = fmaf(xv.x * xv.x, wv.x, s);
        s = fmaf(xv.y * xv.y, wv.y, s);
        s = fmaf(xv.z * xv.z, wv.z, s);
        s = fmaf(xv.w * xv.w, wv.w, s);
    }
    invn[((size_t)(tb * 16 + h) << 8) + n0 + n_l] = 1.0f / (sqrtf(s) + EPSF);
}

// ---------------------------------------------------------------------------
// gram2: attn_t = 0.7 * rownorm(relu(sum_h invn_h (x W2_h x^T) invn_h)) bf16.
// grid = 8 rg x 512 tb = 4096 blocks, 256 threads. LDS 76.5 KB (2 blocks/CU):
//   xs   = bf16(x) 256x128 staged ONCE via async DMA, XOR-16 swizzled
//   wsqS = bf16(w^2) 16x128, invS = bf16(invn) 16x256
// Per h: A-frag = xs row-frag scaled by w^2 (unpack-mul-pack), B-frag raw;
// 16 MFMAs K=128; epilogue att += invr*invc*g.
// ---------------------------------------------------------------------------
__global__ __launch_bounds__(256) void k_gram2(const unsigned short* __restrict__ xb,
                                               const float* __restrict__ Wgl,
                                               const float* __restrict__ invn,
                                               unsigned short* __restrict__ attn) {
    int bid = blockIdx.x;
    int tb = bid & 511;
    int rg = bid >> 9;                  // 0..7
    int n0 = rg << 5;
    int tid = threadIdx.x;
    int wave = tid >> 6, lane = tid & 63;
    int m16 = lane & 15, quad = lane >> 4;

    __shared__ unsigned short xs[256 * 128];     // 64 KB, swizzled
    __shared__ unsigned short wsqS[16 * 128];    // 4 KB
    __shared__ unsigned short invS[16 * 256];    // 8 KB
    __shared__ float rsum[4][32];

    const char* xsB = (const char*)xs;
    const unsigned short* Xb = xb + ((size_t)tb << 15);

    // ---- stage xs via async DMA (swizzle: slot g of row r <- group g^(r&15))
    {
        int lrow_off = lane >> 4;
        int gslot = lane & 15;
        #pragma unroll
        for (int j = 0; j < 16; ++j) {
            int r0 = (wave << 6) + (j << 2);          // wave-uniform
            int grow = r0 + lrow_off;
            int gsw = gslot ^ (grow & 15);
            const unsigned short* src = Xb + (grow << 7) + (gsw << 3);
            gload16(src, xs + (r0 << 7));
        }
    }
    // ---- stage w^2 (bf16) and invn (bf16)
    {
        int h = tid >> 4, c = (tid & 15) << 3;
        const float* wsrc = Wgl + (h << 7) + c;
        float4 wa = *(const float4*)wsrc;
        float4 wb = *(const float4*)(wsrc + 4);
        uint4 o;
        o.x = pack2(f2bf(wa.x * wa.x), f2bf(wa.y * wa.y));
        o.y = pack2(f2bf(wa.z * wa.z), f2bf(wa.w * wa.w));
        o.z = pack2(f2bf(wb.x * wb.x), f2bf(wb.y * wb.y));
        o.w = pack2(f2bf(wb.z * wb.z), f2bf(wb.w * wb.w));
        *(uint4*)(wsqS + (h << 7) + c) = o;
    }
    {
        const float* isrc = invn + ((size_t)tb << 12) + tid * 16;
        #pragma unroll
        for (int k = 0; k < 4; ++k) {
            float4 v = *(const float4*)(isrc + (k << 2));
            uint2 o;
            o.x = pack2(f2bf(v.x), f2bf(v.y));
            o.y = pack2(f2bf(v.z), f2bf(v.w));
            *(uint2*)(invS + tid * 16 + (k << 2)) = o;
        }
    }
    __syncthreads();    // drains DMA too

    f32x4 att[2][4];
    #pragma unroll
    for (int rb = 0; rb < 2; ++rb)
        #pragma unroll
        for (int cb = 0; cb < 4; ++cb) att[rb][cb] = (f32x4){0.f, 0.f, 0.f, 0.f};

    for (int h = 0; h < 16; ++h) {
        f32x4 g[2][4];
        #pragma unroll
        for (int ks = 0; ks < 4; ++ks) {
            int sw = (((ks << 2) | quad) ^ m16) << 4;   // swizzled byte offset
            // w^2 fragment for this lane's 8 d values (broadcast across m16)
            uint4 wu = *(const uint4*)((const char*)wsqS + (h << 8) + (((ks << 2) | quad) << 4));
            float w0 = lo2f(wu.x), w1 = hi2f(wu.x), w2 = lo2f(wu.y), w3 = hi2f(wu.y);
            float w4 = lo2f(wu.z), w5 = hi2f(wu.z), w6 = lo2f(wu.w), w7 = hi2f(wu.w);
            // A-frags: rows n0..n0+31, scaled by w^2
            bf16x8 afr[2];
            #pragma unroll
            for (int rb = 0; rb < 2; ++rb) {
                int row = n0 + (rb << 4) + m16;
                uint4 u = *(const uint4*)(xsB + (row << 8) + sw);
                uint4 o;
                o.x = pkbf(lo2f(u.x) * w0, hi2f(u.x) * w1);
                o.y = pkbf(lo2f(u.y) * w2, hi2f(u.y) * w3);
                o.z = pkbf(lo2f(u.z) * w4, hi2f(u.z) * w5);
                o.w = pkbf(lo2f(u.w) * w6, hi2f(u.w) * w7);
                afr[rb] = *(bf16x8*)&o;
            }
            // B-frags: raw columns
            bf16x8 bfr[4];
            #pragma unroll
            for (int cb = 0; cb < 4; ++cb) {
                int cc = (wave << 6) + (cb << 4) + m16;
                bfr[cb] = *(const bf16x8*)(xsB + (cc << 8) + sw);
            }
            #pragma unroll
            for (int rb = 0; rb < 2; ++rb)
                #pragma unroll
                for (int cb = 0; cb < 4; ++cb) {
                    f32x4 cin = (ks == 0) ? (f32x4){0.f, 0.f, 0.f, 0.f} : g[rb][cb];
                    g[rb][cb] = __builtin_amdgcn_mfma_f32_16x16x32_bf16(afr[rb], bfr[cb], cin, 0, 0, 0);
                }
        }
        // epilogue: att += invr * invc * g
        float invc[4];
        #pragma unroll
        for (int cb = 0; cb < 4; ++cb)
            invc[cb] = bf2f(invS[(h << 8) + (wave << 6) + (cb << 4) + m16]);
        #pragma unroll
        for (int rb = 0; rb < 2; ++rb)
            #pragma unroll
            for (int r = 0; r < 4; ++r) {
                float invr = bf2f(invS[(h << 8) + n0 + (rb << 4) + (quad << 2) + r]);
                #pragma unroll
                for (int cb = 0; cb < 4; ++cb)
                    att[rb][cb][r] = fmaf(invr * invc[cb], g[rb][cb][r], att[rb][cb][r]);
            }
    }

    // relu + rowsum + normalize (x0.7) -> bf16 attn  (relu(S)/16 trick: +16eps)
    float rs[2][4];
    #pragma unroll
    for (int rb = 0; rb < 2; ++rb)
        #pragma unroll
        for (int r = 0; r < 4; ++r) {
            float s = 0.f;
            #pragma unroll
            for (int cb = 0; cb < 4; ++cb) {
                float v = fmaxf(att[rb][cb][r], 0.0f);
                att[rb][cb][r] = v;
                s += v;
            }
            rs[rb][r] = s;
        }
    #pragma unroll
    for (int m = 1; m < 16; m <<= 1)
        #pragma unroll
        for (int rb = 0; rb < 2; ++rb)
            #pragma unroll
            for (int r = 0; r < 4; ++r)
                rs[rb][r] += __shfl_xor(rs[rb][r], m, 64);
    if (m16 == 0) {
        #pragma unroll
        for (int rb = 0; rb < 2; ++rb)
            #pragma unroll
            for (int r = 0; r < 4; ++r)
                rsum[wave][(rb << 4) + (quad << 2) + r] = rs[rb][r];
    }
    __syncthreads();

    unsigned short* outb = attn + ((size_t)tb << 16);
    #pragma unroll
    for (int rb = 0; rb < 2; ++rb) {
        #pragma unroll
        for (int r = 0; r < 4; ++r) {
            int row = (rb << 4) + (quad << 2) + r;
            float tot = rsum[0][row] + rsum[1][row] + rsum[2][row] + rsum[3][row];
            float inv = (1.0f - SKIPF) / (tot + 16.0f * EPSF);
            #pragma unroll
            for (int cb = 0; cb < 4; ++cb) {
                int col = (wave << 6) + (cb << 4) + m16;
                outb[((size_t)(n0 + row) << 8) + col] = f2bf(att[rb][cb][r] * inv);
            }
        }
    }
}

// ---------------------------------------------------------------------------
// scanlast: a=supports; a=0.3a+attn_t; write only A_15 (bf16). grid 2048x256.
// ---------------------------------------------------------------------------
__global__ __launch_bounds__(256) void k_scanlast(const float* __restrict__ supports,
                                                  const unsigned short* __restrict__ AttA,
                                                  unsigned short* __restrict__ Afin) {
    size_t flat = ((size_t)blockIdx.x * 256 + threadIdx.x) * 4;
    float4 s4 = *(const float4*)(supports + flat);
    float a0 = s4.x, a1 = s4.y, a2 = s4.z, a3 = s4.w;
    #pragma unroll
    for (int t = 0; t < TT; ++t) {
        const unsigned short* p = AttA + ((size_t)t << 21) + flat;
        uint2 u = *(const uint2*)p;
        a0 = SKIPF * a0 + bf2f((unsigned short)(u.x & 0xffff));
        a1 = SKIPF * a1 + bf2f((unsigned short)(u.x >> 16));
        a2 = SKIPF * a2 + bf2f((unsigned short)(u.y & 0xffff));
        a3 = SKIPF * a3 + bf2f((unsigned short)(u.y >> 16));
    }
    uint2 o;
    o.x = pack2(f2bf(a0), f2bf(a1));
    o.y = pack2(f2bf(a2), f2bf(a3));
    *(uint2*)(Afin + flat) = o;
}

// NOTE: AttA is indexed [tb][n][m] with tb = t*32+b; scanlast's flat index
// covers b,n,m for fixed t via offset t<<21 — consistent with gram2's tb.

// ---------------------------------------------------------------------------
// hTinit: hT0[b][d][n] = bf16(x15[b][n][d]) for b=0..31. grid 32*32 blocks.
// ---------------------------------------------------------------------------
__global__ __launch_bounds__(256) void k_hTinit(const float* __restrict__ x15,
                                                unsigned short* __restrict__ hT) {
    int bid = blockIdx.x;
    int b = bid >> 5; int r = bid & 31; int d0 = (r >> 3) << 5; int n0 = (r & 7) << 5;
    __shared__ float tl[32][33];
    int tid = threadIdx.x;
    int i = tid >> 5, j = tid & 31;
    #pragma unroll
    for (int s = 0; s < 4; ++s) {
        int nl = (s << 3) + i;
        tl[nl][j] = x15[((size_t)(b * 256 + n0 + nl) << 7) + d0 + j];
    }
    __syncthreads();
    #pragma unroll
    for (int s = 0; s < 4; ++s) {
        int dd = (s << 3) + i;
        hT[((size_t)(b * 128 + d0 + dd) << 8) + n0 + j] = f2bf(tl[j][dd]);
    }
}

// ---------------------------------------------------------------------------
// wprep: bf16-transposed weights WT[dout][k]
// ---------------------------------------------------------------------------
__global__ __launch_bounds__(256) void k_wprep(const float* __restrict__ Wa,
                                               const float* __restrict__ Wr,
                                               const float* __restrict__ Wz,
                                               const float* __restrict__ Wh,
                                               unsigned short* __restrict__ WaT,
                                               unsigned short* __restrict__ WrT,
                                               unsigned short* __restrict__ WzT,
                                               unsigned short* __restrict__ WhT) {
    int idx = blockIdx.x * 256 + threadIdx.x;     // 0..32767
    if (idx < 16384) {
        int dout = idx >> 7, din = idx & 127;
        WaT[idx] = f2bf(Wa[(din << 7) + dout]);
    }
    {
        int dout = idx >> 8, dk = idx & 255;
        WrT[idx] = f2bf(Wr[(dk << 7) + dout]);
        WzT[idx] = f2bf(Wz[(dk << 7) + dout]);
        WhT[idx] = f2bf(Wh[(dk << 7) + dout]);
    }
}

// ---------------------------------------------------------------------------
// step: fused GGNN/GRU step for t=15 only: b = 0..31, 32-row tiles.
// h state in hT (bf16, [b][d][n]). grid = 8 rg x 32 b = 256 blocks.
// ---------------------------------------------------------------------------
__global__ __launch_bounds__(256) void k_step(
    const unsigned short* __restrict__ Afin,
    const unsigned short* __restrict__ hT,
    const unsigned short* __restrict__ WaT, const float* __restrict__ ba,
    const unsigned short* __restrict__ WrT, const float* __restrict__ br,
    const unsigned short* __restrict__ WzT, const float* __restrict__ bz,
    const unsigned short* __restrict__ WhT, const float* __restrict__ bh,
    unsigned short* __restrict__ hT_o) {

    int bid = blockIdx.x;
    int b = bid & 31, rg = bid >> 5;
    int n0 = rg << 5;
    int tid = threadIdx.x;
    int wave = tid >> 6, lane = tid & 63;
    int m16 = lane & 15, quad = lane >> 4;
    int wcol = wave << 5;

    __shared__ unsigned short msgS[32 * 136];
    __shared__ unsigned short ahS[32 * 264];   // k 0..127 = a, 128..255 = h (later r*h)

    const unsigned short* hTb = hT + ((size_t)b << 15);

    // stage h-half of ahS from hT (transpose: ahS[row][128+d] = hT[d][n0+row])
    #pragma unroll
    for (int j = 0; j < 16; ++j) {
        int idx = (j << 8) + tid;            // 0..4095
        int d = idx >> 5, row = idx & 31;
        ahS[row * 264 + 128 + d] = hTb[((size_t)d << 8) + n0 + row];
    }

    // ---- bmm: msg = A_tile @ h  (K=256) ----
    f32x4 acc[2][2];
    #pragma unroll
    for (int rb = 0; rb < 2; ++rb)
        #pragma unroll
        for (int cb = 0; cb < 2; ++cb) acc[rb][cb] = (f32x4){0.f, 0.f, 0.f, 0.f};

    const unsigned short* Ab = Afin + ((size_t)b << 16) + ((size_t)n0 << 8);
    #pragma unroll 2
    for (int ks = 0; ks < 8; ++ks) {
        bf16x8 af[2], bf[2];
        #pragma unroll
        for (int rb = 0; rb < 2; ++rb)
            af[rb] = *(const bf16x8*)(Ab + (((rb << 4) + m16) << 8) + (ks << 5) + (quad << 3));
        #pragma unroll
        for (int cb = 0; cb < 2; ++cb)
            bf[cb] = *(const bf16x8*)(hTb + ((wcol + (cb << 4) + m16) << 8) + (ks << 5) + (quad << 3));
        #pragma unroll
        for (int rb = 0; rb < 2; ++rb)
            #pragma unroll
            for (int cb = 0; cb < 2; ++cb)
                acc[rb][cb] = __builtin_amdgcn_mfma_f32_16x16x32_bf16(af[rb], bf[cb], acc[rb][cb], 0, 0, 0);
    }
    #pragma unroll
    for (int rb = 0; rb < 2; ++rb)
        #pragma unroll
        for (int cb = 0; cb < 2; ++cb)
            #pragma unroll
            for (int r = 0; r < 4; ++r)
                msgS[((rb << 4) + (quad << 2) + r) * 136 + wcol + (cb << 4) + m16] = f2bf(acc[rb][cb][r]);
    __syncthreads();   // covers h-half staging too

    // ---- a = msg @ Wa + ba ----
    #pragma unroll
    for (int rb = 0; rb < 2; ++rb)
        #pragma unroll
        for (int cb = 0; cb < 2; ++cb) acc[rb][cb] = (f32x4){0.f, 0.f, 0.f, 0.f};
    #pragma unroll
    for (int ks = 0; ks < 4; ++ks) {
        bf16x8 af[2], bf[2];
        #pragma unroll
        for (int rb = 0; rb < 2; ++rb)
            af[rb] = *(const bf16x8*)(msgS + ((rb << 4) + m16) * 136 + (ks << 5) + (quad << 3));
        #pragma unroll
        for (int cb = 0; cb < 2; ++cb)
            bf[cb] = *(const bf16x8*)(WaT + ((wcol + (cb << 4) + m16) << 7) + (ks << 5) + (quad << 3));
        #pragma unroll
        for (int rb = 0; rb < 2; ++rb)
            #pragma unroll
            for (int cb = 0; cb < 2; ++cb)
                acc[rb][cb] = __builtin_amdgcn_mfma_f32_16x16x32_bf16(af[rb], bf[cb], acc[rb][cb], 0, 0, 0);
    }
    {
        float bav[2];
        #pragma unroll
        for (int cb = 0; cb < 2; ++cb) bav[cb] = ba[wcol + (cb << 4) + m16];
        #pragma unroll
        for (int rb = 0; rb < 2; ++rb)
            #pragma unroll
            for (int cb = 0; cb < 2; ++cb)
                #pragma unroll
                for (int r = 0; r < 4; ++r)
                    ahS[((rb << 4) + (quad << 2) + r) * 264 + wcol + (cb << 4) + m16] =
                        f2bf(acc[rb][cb][r] + bav[cb]);
    }
    __syncthreads();

    // h_old (for r*h and final update): uint2 = 4 consecutive n at fixed col
    float hv[2][2][4];
    #pragma unroll
    for (int rb = 0; rb < 2; ++rb)
        #pragma unroll
        for (int cb = 0; cb < 2; ++cb) {
            int col = wcol + (cb << 4) + m16;
            uint2 u = *(const uint2*)(hTb + ((size_t)col << 8) + n0 + (rb << 4) + (quad << 2));
            hv[rb][cb][0] = bf2f((unsigned short)(u.x & 0xffff));
            hv[rb][cb][1] = bf2f((unsigned short)(u.x >> 16));
            hv[rb][cb][2] = bf2f((unsigned short)(u.y & 0xffff));
            hv[rb][cb][3] = bf2f((unsigned short)(u.y >> 16));
        }

    // ---- r and z ----
    f32x4 racc[2][2], zacc[2][2];
    #pragma unroll
    for (int rb = 0; rb < 2; ++rb)
        #pragma unroll
        for (int cb = 0; cb < 2; ++cb) {
            racc[rb][cb] = (f32x4){0.f, 0.f, 0.f, 0.f};
            zacc[rb][cb] = (f32x4){0.f, 0.f, 0.f, 0.f};
        }
    #pragma unroll 2
    for (int ks = 0; ks < 8; ++ks) {
        bf16x8 af[2], bfr[2], bfz[2];
        #pragma unroll
        for (int rb = 0; rb < 2; ++rb)
            af[rb] = *(const bf16x8*)(ahS + ((rb << 4) + m16) * 264 + (ks << 5) + (quad << 3));
        #pragma unroll
        for (int cb = 0; cb < 2; ++cb) {
            int dout = wcol + (cb << 4) + m16;
            bfr[cb] = *(const bf16x8*)(WrT + (dout << 8) + (ks << 5) + (quad << 3));
            bfz[cb] = *(const bf16x8*)(WzT + (dout << 8) + (ks << 5) + (quad << 3));
        }
        #pragma unroll
        for (int rb = 0; rb < 2; ++rb)
            #pragma unroll
            for (int cb = 0; cb < 2; ++cb) {
                racc[rb][cb] = __builtin_amdgcn_mfma_f32_16x16x32_bf16(af[rb], bfr[cb], racc[rb][cb], 0, 0, 0);
                zacc[rb][cb] = __builtin_amdgcn_mfma_f32_16x16x32_bf16(af[rb], bfz[cb], zacc[rb][cb], 0, 0, 0);
            }
    }
    float zv[2][2][4];
    {
        float brv[2], bzv[2];
        #pragma unroll
        for (int cb = 0; cb < 2; ++cb) {
            brv[cb] = br[wcol + (cb << 4) + m16];
            bzv[cb] = bz[wcol + (cb << 4) + m16];
        }
        #pragma unroll
        for (int rb = 0; rb < 2; ++rb)
            #pragma unroll
            for (int cb = 0; cb < 2; ++cb)
                #pragma unroll
                for (int r = 0; r < 4; ++r) {
                    racc[rb][cb][r] = sigmoidf_(racc[rb][cb][r] + brv[cb]);
                    zv[rb][cb][r]  = sigmoidf_(zacc[rb][cb][r] + bzv[cb]);
                }
    }
    __syncthreads();   // all ahS reads done -> safe to overwrite h-half

    #pragma unroll
    for (int rb = 0; rb < 2; ++rb)
        #pragma unroll
        for (int cb = 0; cb < 2; ++cb)
            #pragma unroll
            for (int r = 0; r < 4; ++r)
                ahS[((rb << 4) + (quad << 2) + r) * 264 + 128 + wcol + (cb << 4) + m16] =
                    f2bf(racc[rb][cb][r] * hv[rb][cb][r]);
    __syncthreads();

    // ---- h_tilde ----
    #pragma unroll
    for (int rb = 0; rb < 2; ++rb)
        #pragma unroll
        for (int cb = 0; cb < 2; ++cb) acc[rb][cb] = (f32x4){0.f, 0.f, 0.f, 0.f};
    #pragma unroll 2
    for (int ks = 0; ks < 8; ++ks) {
        bf16x8 af[2], bf[2];
        #pragma unroll
        for (int rb = 0; rb < 2; ++rb)
            af[rb] = *(const bf16x8*)(ahS + ((rb << 4) + m16) * 264 + (ks << 5) + (quad << 3));
        #pragma unroll
        for (int cb = 0; cb < 2; ++cb)
            bf[cb] = *(const bf16x8*)(WhT + ((wcol + (cb << 4) + m16) << 8) + (ks << 5) + (quad << 3));
        #pragma unroll
        for (int rb = 0; rb < 2; ++rb)
            #pragma unroll
            for (int cb = 0; cb < 2; ++cb)
                acc[rb][cb] = __builtin_amdgcn_mfma_f32_16x16x32_bf16(af[rb], bf[cb], acc[rb][cb], 0, 0, 0);
    }

    // ---- update + writes (hT only) ----
    {
        float bhv[2];
        #pragma unroll
        for (int cb = 0; cb < 2; ++cb) bhv[cb] = bh[wcol + (cb << 4) + m16];
        #pragma unroll
        for (int rb = 0; rb < 2; ++rb)
            #pragma unroll
            for (int cb = 0; cb < 2; ++cb) {
                int col = wcol + (cb << 4) + m16;
                unsigned short pk[4];
                #pragma unroll
                for (int r = 0; r < 4; ++r) {
                    float ht = tanhf_(acc[rb][cb][r] + bhv[cb]);
                    float hn = hv[rb][cb][r] + zv[rb][cb][r] * (ht - hv[rb][cb][r]);
                    pk[r] = f2bf(hn);
                }
                uint2 p;
                p.x = pack2(pk[0], pk[1]); p.y = pack2(pk[2], pk[3]);
                *(uint2*)(hT_o + ((size_t)(b * 128 + col) << 8) + n0 + (rb << 4) + (quad << 2)) = p;
            }
    }
}

// ---------------------------------------------------------------------------
// fc: logits[b,c] = sum over col-major h (hT1, b slice) + bfc. grid = 512.
// ---------------------------------------------------------------------------
__global__ __launch_bounds__(256) void k_fc(const unsigned short* __restrict__ hT,
                                            const float* __restrict__ Wfc,
                                            const float* __restrict__ bfc,
                                            float* __restrict__ out) {
    int bid = blockIdx.x;
    int b = bid >> 4, part = bid & 15;
    int tid = threadIdx.x;
    const unsigned short* hp = hT + ((size_t)b << 15);
    int i = part * 2048 + tid * 8;       // linear col-major: i = d*256 + n
    int d = i >> 8, n = i & 255;
    uint4 hu = *(const uint4*)(hp + i);
    unsigned short hs[8];
    hs[0] = hu.x & 0xffff; hs[1] = hu.x >> 16;
    hs[2] = hu.y & 0xffff; hs[3] = hu.y >> 16;
    hs[4] = hu.z & 0xffff; hs[5] = hu.z >> 16;
    hs[6] = hu.w & 0xffff; hs[7] = hu.w >> 16;
    float a0 = 0.f, a1 = 0.f;
    #pragma unroll
    for (int k = 0; k < 8; ++k) {
        float v = bf2f(hs[k]);
        const float2 w = *(const float2*)(Wfc + ((size_t)(n + k) * 128 + d) * 2);
        a0 = fmaf(v, w.x, a0);
        a1 = fmaf(v, w.y, a1);
    }
    int wave = tid >> 6, lane = tid & 63;
    #pragma unroll
    for (int off = 32; off; off >>= 1) {
        a0 += __shfl_down(a0, off, 64);
        a1 += __shfl_down(a1, off, 64);
    }
    __shared__ float r0[4], r1[4];
    if (lane == 0) { r0[wave] = a0; r1[wave] = a1; }
    __syncthreads();
    if (tid == 0) {
        float s0 = r0[0] + r0[1] + r0[2] + r0[3];
        float s1 = r1[0] + r1[1] + r1[2] + r1[3];
        if (part == 0) { s0 += bfc[0]; s1 += bfc[1]; }
        atomicAdd(&out[b * 2 + 0], s0);
        atomicAdd(&out[b * 2 + 1], s1);
    }
}

// ---------------------------------------------------------------------------
extern "C" void kernel_launch(void* const* d_in, const int* in_sizes, int n_in,
                              void* d_out, int out_size, void* d_ws, size_t ws_size,
                              hipStream_t stream) {
    const float* x_all    = (const float*)d_in[0];
    const float* supports = (const float*)d_in[1];
    const float* Wgl = (const float*)d_in[2];
    const float* Wa  = (const float*)d_in[3];
    const float* ba  = (const float*)d_in[4];
    const float* Wr  = (const float*)d_in[5];
    const float* br  = (const float*)d_in[6];
    const float* Wz  = (const float*)d_in[7];
    const float* bz  = (const float*)d_in[8];
    const float* Wh  = (const float*)d_in[9];
    const float* bh  = (const float*)d_in[10];
    const float* Wfc = (const float*)d_in[11];
    const float* bfc = (const float*)d_in[12];
    float* out = (float*)d_out;

    char* p = (char*)d_ws;
    auto alloc = [&](size_t bytes) { char* r = p; p += (bytes + 255) & ~(size_t)255; return r; };

    unsigned short* AttA = (unsigned short*)alloc((size_t)TT * BB * NN * NN * 2);  // 64 MB
    unsigned short* xb   = (unsigned short*)alloc((size_t)TT * BB * NN * DD * 2);  // 32 MB
    float* invn          = (float*)alloc((size_t)TT * BB * 16 * NN * 4);           // 8 MB
    unsigned short* Afin = (unsigned short*)alloc((size_t)BB * NN * NN * 2);       // 4 MB
    unsigned short* hT0  = (unsigned short*)alloc((size_t)BB * DD * NN * 2);       // 2 MB
    unsigned short* hT1  = (unsigned short*)alloc((size_t)BB * DD * NN * 2);       // 2 MB
    unsigned short* WaT  = (unsigned short*)alloc(128 * 128 * 2);
    unsigned short* WrT  = (unsigned short*)alloc(256 * 128 * 2);
    unsigned short* WzT  = (unsigned short*)alloc(256 * 128 * 2);
    unsigned short* WhT  = (unsigned short*)alloc(256 * 128 * 2);
    // total ~112.5 MB

    k_wprep<<<128, 256, 0, stream>>>(Wa, Wr, Wz, Wh, WaT, WrT, WzT, WhT);
    k_xbf<<<16384, 256, 0, stream>>>(x_all, xb);
    k_norms<<<TT * BB * 16, 256, 0, stream>>>(x_all, Wgl, invn);

    // attention path: all 16 t in one dispatch
    k_gram2<<<8 * TT * BB, 256, 0, stream>>>(xb, Wgl, invn, AttA);
    k_scanlast<<<2048, 256, 0, stream>>>(supports, AttA, Afin);

    // GRU path: ONLY t=15 is live (reference uses outs[-1] only)
    const float* x15 = x_all + (size_t)15 * BB * NN * DD;
    k_hTinit<<<BB * 32, 256, 0, stream>>>(x15, hT0);

    const unsigned short* hT_in = hT0;
    for (int s = 0; s < NSTEPS; ++s) {
        unsigned short* hTo = (s & 1) ? hT0 : hT1;
        k_step<<<8 * BB, 256, 0, stream>>>(Afin, hT_in,
                                           WaT, ba, WrT, br, WzT, bz, WhT, bh,
                                           hTo);
        hT_in = hTo;
    }
    // after 5 steps (s=4) final h is in hT1
    hipMemsetAsync(d_out, 0, (size_t)out_size * sizeof(float), stream);
    k_fc<<<BB * 16, 256, 0, stream>>>(hT1, Wfc, bfc, out);
}